// Round 1
// baseline (492.974 us; speedup 1.0000x reference)
//
#include <hip/hip_runtime.h>

#define HALO 10
#define NIMG 48                 // 16 batch * 3 channels

// Gaussian(sigma=1.5, 11 taps), normalized (computed offline in double).
#define GWLIST { 0.0010284f, 0.0075987f, 0.0360008f, 0.1093607f, 0.2130056f, \
                 0.2660117f, 0.2130056f, 0.1093607f, 0.0360008f, 0.0075987f, 0.0010284f }

// ---- MFMA-path LDS layout (fp16), identical to previous version ----------
#define PP   56                 // stage-1 plane pitch (fp16 units)
#define PSZ  (48 * 56)          // plane size = 2688 fp16
#define HTP  56                 // h_T pitch along r (fp16 units)
#define HTSZ (32 * 56)          // per-quantity h_T = 1792 fp16
#define WT0  (5 * PSZ)          // wfrag table offset = 13440 (byte 26880)
#define LDSH (WT0 + 64 * 8)     // 13952 fp16 = 27904 B

// ---- scalar-path LDS layout (fp32), aliases bytes [0, 26880) of sm -------
#define TH   32
#define ROWS (TH + HALO)        // 42
#define HSTR 32
#define HQ   (ROWS * HSTR)      // 1344 floats

// ---- workspace layout -----------------------------------------------------
// [0, 130944)        : 16368 float2 partials
// [204800, 204864)   : grid-barrier counter (memset to 0 each launch)
// [262144, ...)      : pyramid buffers
#define CNT_OFF (200 * 1024)
#define PYR_OFF (1 << 18)

typedef _Float16 half8 __attribute__((ext_vector_type(8)));
typedef _Float16 half4 __attribute__((ext_vector_type(4)));
typedef float    floatx4 __attribute__((ext_vector_type(4)));

// ---------------- device-scope grid barrier --------------------------------
// Monotonic single counter; target = k*gridDim.x for the k-th barrier.
// Correct across XCDs: device-scope atomics resolve at the common point;
// agent-scope __threadfence does L2 writeback (release) / invalidate (acquire).
__device__ __forceinline__ void grid_sync(unsigned* cnt, unsigned target)
{
    __syncthreads();
    if (threadIdx.x == 0) {
        __threadfence();                 // release: push this block's writes
        atomicAdd(cnt, 1u);              // device-scope arrive
        while (__hip_atomic_load(cnt, __ATOMIC_RELAXED,
                                 __HIP_MEMORY_SCOPE_AGENT) < target)
            __builtin_amdgcn_s_sleep(8);
        __threadfence();                 // acquire: see other blocks' writes
    }
    __syncthreads();
}

// ======================= MFMA tile body (scales 0,1) =======================
// Identical math/order to the verified ssim_mfma_kernel (absmax 0.0).
// wfrag table is prebuilt once per block (persistent LDS).
__device__ __forceinline__ void mfma_tile(
    const float* __restrict__ a, const float* __restrict__ b,
    const int H, const int W, const int gx0, const int gy0, const int z,
    float2* __restrict__ partial, const int slot,
    float* __restrict__ poolA, float* __restrict__ poolB,
    _Float16* __restrict__ sm, float* __restrict__ red)
{
    const int tid  = threadIdx.x;
    const int lane = tid & 63;
    const int wv   = tid >> 6;

    // ---- stage 1: 48x48 region -> 5 fp16 quantity planes ----------------
    const bool fast = (gy0 + 48 <= H) && (gx0 + 48 <= W);
    for (int e = tid; e < 288; e += 256) {        // 48 rows x 6 col-octets
        int r = e / 6, c8 = e - r * 6;
        float fa[8], fb[8];
        if (fast) {
            const float* pa = a + (size_t)(gy0 + r) * W + gx0 + c8 * 8;
            const float* pb = b + (size_t)(gy0 + r) * W + gx0 + c8 * 8;
            *(float4*)&fa[0] = *(const float4*)pa;
            *(float4*)&fa[4] = *(const float4*)(pa + 4);
            *(float4*)&fb[0] = *(const float4*)pb;
            *(float4*)&fb[4] = *(const float4*)(pb + 4);
        } else {
            int gy = gy0 + r;
            #pragma unroll
            for (int i = 0; i < 8; ++i) {
                int gx = gx0 + c8 * 8 + i;
                bool ok = (gy < H) && (gx < W);
                size_t idx = (size_t)gy * W + gx;
                fa[i] = ok ? a[idx] : 0.f;
                fb[i] = ok ? b[idx] : 0.f;
            }
        }
        half8 ha, hb;
        #pragma unroll
        for (int i = 0; i < 8; ++i) {
            ha[i] = (_Float16)fa[i];
            hb[i] = (_Float16)fb[i];
        }
        half8 haa = ha * ha;
        half8 hbb = hb * hb;
        half8 hab = ha * hb;
        int o = r * PP + c8 * 8;
        *(half8*)&sm[o + 0 * PSZ] = ha;
        *(half8*)&sm[o + 1 * PSZ] = hb;
        *(half8*)&sm[o + 2 * PSZ] = haa;
        *(half8*)&sm[o + 3 * PSZ] = hbb;
        *(half8*)&sm[o + 4 * PSZ] = hab;
    }
    __syncthreads();

    const half8 wfrag = *(const half8*)&sm[WT0 + lane * 8];

    // ---- stage 2a: h-conv via MFMA, results held in registers -----------
    half4 res[8];
    {
        const int arow = (lane & 15) * PP + ((lane >> 4) << 3);
        #pragma unroll
        for (int u = 0; u < 8; ++u) {
            int jj = wv + 4 * u;
            if (jj < 30) {                        // wave-uniform
                int q = jj / 6, rem = jj - q * 6;
                int m0 = (rem >> 1) << 4;
                int x0 = (rem & 1) << 4;
                half8 afrag = *(const half8*)&sm[q * PSZ + m0 * PP + x0 + arow];
                floatx4 c = {0.f, 0.f, 0.f, 0.f};
                c = __builtin_amdgcn_mfma_f32_16x16x32_f16(afrag, wfrag, c, 0, 0, 0);
                half4 hv;
                hv[0] = (_Float16)c[0]; hv[1] = (_Float16)c[1];
                hv[2] = (_Float16)c[2]; hv[3] = (_Float16)c[3];
                res[u] = hv;
            }
        }
    }
    __syncthreads();      // all plane reads done; plane region now reusable

    // ---- stage 2b: write transposed fp16 h_T into (dead) plane region ---
    {
        const int crow = (lane & 15) * HTP + ((lane >> 4) << 2);
        #pragma unroll
        for (int u = 0; u < 8; ++u) {
            int jj = wv + 4 * u;
            if (jj < 30) {
                int q = jj / 6, rem = jj - q * 6;
                int m0 = (rem >> 1) << 4;
                int x0 = (rem & 1) << 4;
                *(half4*)&sm[q * HTSZ + x0 * HTP + m0 + crow] = res[u];
            }
        }
    }
    __syncthreads();

    // ---- stage 3: v-conv via MFMA + SSIM --------------------------------
    float csSum = 0.f, ssimSum = 0.f;
    {
        const int y0 = (wv >> 1) << 4;
        const int x0 = (wv & 1) << 4;
        const int brow = (lane & 15) * HTP + ((lane >> 4) << 3);
        floatx4 m[5];
        #pragma unroll
        for (int q = 0; q < 5; ++q) {
            half8 bfrag = *(const half8*)&sm[q * HTSZ + x0 * HTP + y0 + brow];
            floatx4 c = {0.f, 0.f, 0.f, 0.f};
            m[q] = __builtin_amdgcn_mfma_f32_16x16x32_f16(wfrag, bfrag, c, 0, 0, 0);
        }
        const int OH = H - HALO, OW = W - HALO;
        const int gx  = gx0 + x0 + (lane & 15);
        const int gyb = gy0 + y0 + ((lane >> 4) << 2);
        const float C1 = 1e-4f;   // (0.01*1)^2
        const float C2 = 9e-4f;   // (0.03*1)^2
        if (gx < OW) {
            #pragma unroll
            for (int i = 0; i < 4; ++i) {
                int gy = gyb + i;
                if (gy < OH) {
                    float mu1 = m[0][i], mu2 = m[1][i];
                    float s1sq = m[2][i] - mu1 * mu1;
                    float s2sq = m[3][i] - mu2 * mu2;
                    float s12  = m[4][i] - mu1 * mu2;
                    float denom = s1sq + s2sq + C2;
                    float num   = 2.f * s12 + C2;
                    float csv = num * __frcp_rn(denom);
                    float ssv = csv * (2.f * mu1 * mu2 + C1) *
                                __frcp_rn(mu1 * mu1 + mu2 * mu2 + C1);
                    csSum   += csv;
                    ssimSum += ssv;
                }
            }
        }
    }

    // ---- block reduction -> per-block partial slot ----------------------
    #pragma unroll
    for (int off = 32; off > 0; off >>= 1) {
        csSum   += __shfl_down(csSum, off, 64);
        ssimSum += __shfl_down(ssimSum, off, 64);
    }
    if (lane == 0) {
        red[wv]     = csSum;
        red[8 + wv] = ssimSum;
    }
    __syncthreads();
    if (tid == 0) {
        float c = 0.f, s = 0.f;
        #pragma unroll
        for (int i = 0; i < 4; ++i) { c += red[i]; s += red[8 + i]; }
        partial[slot] = make_float2(c, s);
    }

    // ---- fused 2x2 avg-pool of this block's own 32x32 input region ------
    if (tid < 128) {
        const int OH2 = H >> 1, OW2 = W >> 1;
        const int img = tid >> 6;            // 0 = A, 1 = B
        const int rem = tid & 63;
        const int pr  = rem >> 2;            // pooled row 0..15
        const int pq  = rem & 3;             // pooled float4-col 0..3
        const float* src = img ? b : a;
        float* dst = (img ? poolB : poolA) + (size_t)z * OH2 * OW2;
        size_t base = (size_t)(gy0 + 2 * pr) * W + gx0 + pq * 8;
        float4 r0 = *(const float4*)(src + base);
        float4 r1 = *(const float4*)(src + base + 4);
        float4 r2 = *(const float4*)(src + base + W);
        float4 r3 = *(const float4*)(src + base + W + 4);
        float4 o;
        o.x = 0.25f * (r0.x + r0.y + r2.x + r2.y);
        o.y = 0.25f * (r0.z + r0.w + r2.z + r2.w);
        o.z = 0.25f * (r1.x + r1.y + r3.x + r3.y);
        o.w = 0.25f * (r1.z + r1.w + r3.z + r3.w);
        *(float4*)(dst + (size_t)((gy0 >> 1) + pr) * OW2 + (gx0 >> 1) + pq * 4) = o;
    }
}

// ================= exact fp32 scalar tile body (scales 2-4) ================
__device__ __forceinline__ void scalar_tile(
    const float* __restrict__ a, const float* __restrict__ b,
    const int H, const int W, const int gx0, const int gy0, const int z,
    float2* __restrict__ partial, const int slot,
    float* __restrict__ poolA, float* __restrict__ poolB, const bool fuse,
    float* __restrict__ lds, float* __restrict__ red)
{
    const float w[11] = GWLIST;
    const int tid = threadIdx.x;

    const bool fast = (gy0 + ROWS <= H) && (gx0 + 44 <= W);
    for (int e = tid; e < ROWS * 8; e += 256) {
        int r = e >> 3, c0 = (e & 7) * 4;
        int gy = gy0 + r;
        float s1[4]  = {0.f, 0.f, 0.f, 0.f};
        float s2[4]  = {0.f, 0.f, 0.f, 0.f};
        float s11[4] = {0.f, 0.f, 0.f, 0.f};
        float s22[4] = {0.f, 0.f, 0.f, 0.f};
        float s12[4] = {0.f, 0.f, 0.f, 0.f};
        #pragma unroll
        for (int c = 0; c < 4; ++c) {
            float ea[4], eb[4];
            if (fast) {
                const float* pa = a + (size_t)gy * W + gx0 + c0 + 4 * c;
                const float* pb = b + (size_t)gy * W + gx0 + c0 + 4 * c;
                *(float4*)&ea[0] = *(const float4*)pa;
                *(float4*)&eb[0] = *(const float4*)pb;
            } else {
                #pragma unroll
                for (int t = 0; t < 4; ++t) {
                    int gx = gx0 + c0 + 4 * c + t;
                    bool ok = (gy < H) && (gx < W);
                    size_t idx = (size_t)gy * W + gx;
                    ea[t] = ok ? a[idx] : 0.f;
                    eb[t] = ok ? b[idx] : 0.f;
                }
            }
            #pragma unroll
            for (int mm = 0; mm < 4; ++mm) {
                const int i = 4 * c + mm;
                float va = ea[mm], vb = eb[mm];
                float vaa = va * va, vbb = vb * vb, vab = va * vb;
                #pragma unroll
                for (int k = 0; k < 4; ++k) {
                    const int j = i - k;
                    if (j >= 0 && j <= 10) {
                        float wj = w[j];
                        s1[k]  += wj * va;
                        s2[k]  += wj * vb;
                        s11[k] += wj * vaa;
                        s22[k] += wj * vbb;
                        s12[k] += wj * vab;
                    }
                }
            }
        }
        int hb = r * HSTR + c0;
        *(float4*)&lds[hb + 0 * HQ] = make_float4(s1[0],  s1[1],  s1[2],  s1[3]);
        *(float4*)&lds[hb + 1 * HQ] = make_float4(s2[0],  s2[1],  s2[2],  s2[3]);
        *(float4*)&lds[hb + 2 * HQ] = make_float4(s11[0], s11[1], s11[2], s11[3]);
        *(float4*)&lds[hb + 3 * HQ] = make_float4(s22[0], s22[1], s22[2], s22[3]);
        *(float4*)&lds[hb + 4 * HQ] = make_float4(s12[0], s12[1], s12[2], s12[3]);
    }
    __syncthreads();

    const float C1 = 1e-4f;
    const float C2 = 9e-4f;
    float csSum = 0.f, ssimSum = 0.f;
    {
        const int ox  = tid & 31;
        const int oy0 = (tid >> 5) * 4;
        float m[5][4];
        #pragma unroll
        for (int q = 0; q < 5; ++q) {
            const float* hq = &lds[q * HQ + oy0 * HSTR + ox];
            float win[14];
            #pragma unroll
            for (int i = 0; i < 14; ++i) win[i] = hq[i * HSTR];
            #pragma unroll
            for (int k = 0; k < 4; ++k) {
                float acc = 0.f;
                #pragma unroll
                for (int j = 0; j < 11; ++j) acc += w[j] * win[k + j];
                m[q][k] = acc;
            }
        }
        const int OH = H - HALO, OW = W - HALO;
        const int gx = gx0 + ox;
        #pragma unroll
        for (int k = 0; k < 4; ++k) {
            int gy = gy0 + oy0 + k;
            if (gy < OH && gx < OW) {
                float mu1 = m[0][k], mu2 = m[1][k];
                float s1sq = m[2][k] - mu1 * mu1;
                float s2sq = m[3][k] - mu2 * mu2;
                float s12  = m[4][k] - mu1 * mu2;
                float denom  = s1sq + s2sq + C2;
                float num_cs = 2.f * s12 + C2;
                float csv = num_cs * __frcp_rn(denom);
                float ssv = csv * (2.f * mu1 * mu2 + C1) *
                            __frcp_rn(mu1 * mu1 + mu2 * mu2 + C1);
                csSum   += csv;
                ssimSum += ssv;
            }
        }
    }

    #pragma unroll
    for (int off = 32; off > 0; off >>= 1) {
        csSum   += __shfl_down(csSum, off, 64);
        ssimSum += __shfl_down(ssimSum, off, 64);
    }
    int wave = tid >> 6, lane = tid & 63;
    if (lane == 0) {
        red[wave]     = csSum;
        red[8 + wave] = ssimSum;
    }
    __syncthreads();
    if (tid == 0) {
        float c = 0.f, s = 0.f;
        #pragma unroll
        for (int i = 0; i < 4; ++i) { c += red[i]; s += red[8 + i]; }
        partial[slot] = make_float2(c, s);
    }

    if (fuse && tid < 128) {
        const int OH2 = H >> 1, OW2 = W >> 1;
        const int img = tid >> 6;
        const int rem = tid & 63;
        const int pr  = rem >> 2;
        const int pq  = rem & 3;
        const float* src = img ? b : a;
        float* dst = (img ? poolB : poolA) + (size_t)z * OH2 * OW2;
        size_t base = (size_t)(gy0 + 2 * pr) * W + gx0 + pq * 8;
        float4 r0 = *(const float4*)(src + base);
        float4 r1 = *(const float4*)(src + base + 4);
        float4 r2 = *(const float4*)(src + base + W);
        float4 r3 = *(const float4*)(src + base + W + 4);
        float4 o;
        o.x = 0.25f * (r0.x + r0.y + r2.x + r2.y);
        o.y = 0.25f * (r0.z + r0.w + r2.z + r2.w);
        o.z = 0.25f * (r1.x + r1.y + r3.x + r3.y);
        o.w = 0.25f * (r1.z + r1.w + r3.z + r3.w);
        *(float4*)(dst + (size_t)((gy0 >> 1) + pr) * OW2 + (gx0 >> 1) + pq * 4) = o;
    }
}

// ---------------- final reduction (block 0 only) ---------------------------
__device__ __forceinline__ void final_reduce(const float2* __restrict__ partial,
                                             float* __restrict__ out,
                                             _Float16* __restrict__ smraw)
{
    double* dred = (double*)smraw;       // 8 doubles
    double* resC = dred + 8;             // 5
    double* resS = dred + 13;            // 5
    const int segs[6] = {0, 12288, 15360, 16128, 16320, 16368};
    const int tid = threadIdx.x;
    for (int s = 0; s < 5; ++s) {
        double c = 0.0, v = 0.0;
        #pragma unroll 4
        for (int i = segs[s] + tid; i < segs[s + 1]; i += 256) {
            float2 p = partial[i];
            c += (double)p.x;
            v += (double)p.y;
        }
        #pragma unroll
        for (int off = 32; off > 0; off >>= 1) {
            c += __shfl_down(c, off, 64);
            v += __shfl_down(v, off, 64);
        }
        int wave = tid >> 6, lane = tid & 63;
        __syncthreads();
        if (lane == 0) { dred[wave] = c; dred[4 + wave] = v; }
        __syncthreads();
        if (tid == 0) {
            resC[s] = dred[0] + dred[1] + dred[2] + dred[3];
            resS[s] = dred[4] + dred[5] + dred[6] + dred[7];
        }
    }
    __syncthreads();
    if (tid == 0) {
        const double wgt[5] = {0.0448, 0.2856, 0.3001, 0.2363, 0.1333};
        double ms = 1.0;
        for (int s = 0; s < 5; ++s) {
            int Hs = 512 >> s;
            double cnt = (double)NIMG * (double)(Hs - 10) * (double)(Hs - 10);
            double cs = resC[s] / cnt;
            double sv = resS[s] / cnt;
            if (cs < 0.0) cs = 0.0;
            if (sv < 0.0) sv = 0.0;
            cs = (cs + 1.0) * 0.5;
            sv = (sv + 1.0) * 0.5;
            ms *= pow((s < 4) ? cs : sv, wgt[s]);
        }
        out[0] = (float)(1.0 - ms);
    }
}

// ===================== single persistent fused kernel ======================
__global__ __launch_bounds__(256, 5) void ms_ssim_fused(
    const float* __restrict__ A0, const float* __restrict__ B0,
    char* __restrict__ ws, float* __restrict__ out)
{
    __shared__ __align__(16) _Float16 sm[LDSH];   // 27904 B (scalar path aliases [0,26880) as fp32)
    __shared__ float red[16];

    float2*   partial = (float2*)ws;
    float*    pyr     = (float*)(ws + PYR_OFF);
    unsigned* cnt     = (unsigned*)(ws + CNT_OFF);

    const size_t n1 = (size_t)NIMG * 256 * 256;
    const size_t n2 = (size_t)NIMG * 128 * 128;
    const size_t n3 = (size_t)NIMG * 64 * 64;
    float* pa1 = pyr;        float* pb1 = pa1 + n1;
    float* pa2 = pb1 + n1;   float* pb2 = pa2 + n2;
    float* pa3 = pb2 + n2;   float* pb3 = pa3 + n3;
    float* pa4 = pb3 + n3;   float* pb4 = pa4 + (size_t)NIMG * 32 * 32;

    // ---- wave 0: build band-weight fragment table ONCE per block --------
    // (lives at sm bytes [26880,27904), above the scalar path's fp32 region,
    //  so it survives every tile of every scale; first consumer is behind
    //  the first tile's stage-1 __syncthreads.)
    if (threadIdx.x < 64) {
        const float w[11] = GWLIST;
        int base = ((threadIdx.x >> 4) << 3) - (threadIdx.x & 15);
        half8 wf;
        #pragma unroll
        for (int i = 0; i < 8; ++i) {
            int j = base + i;
            float v = 0.f;
            #pragma unroll
            for (int J = 0; J < 11; ++J) v = (j == J) ? w[J] : v;
            wf[i] = (_Float16)v;
        }
        *(half8*)&sm[WT0 + threadIdx.x * 8] = wf;
    }

    const int nb = (int)gridDim.x;

    // ---- scale 0: 512x512, 16x16x48 = 12288 tiles (MFMA path) -----------
    for (int t = blockIdx.x; t < 12288; t += nb) {
        int z = t >> 8, rem = t & 255;
        int by = rem >> 4, bx = rem & 15;
        mfma_tile(A0 + (size_t)z * (512 * 512), B0 + (size_t)z * (512 * 512),
                  512, 512, bx * 32, by * 32, z,
                  partial, t, pa1, pb1, sm, red);
    }
    grid_sync(cnt, (unsigned)nb);

    // ---- scale 1: 256x256, 8x8x48 = 3072 tiles (MFMA path) --------------
    for (int t = blockIdx.x; t < 3072; t += nb) {
        int z = t >> 6, rem = t & 63;
        int by = rem >> 3, bx = rem & 7;
        mfma_tile(pa1 + (size_t)z * (256 * 256), pb1 + (size_t)z * (256 * 256),
                  256, 256, bx * 32, by * 32, z,
                  partial, 12288 + t, pa2, pb2, sm, red);
    }
    grid_sync(cnt, 2u * nb);

    // ---- scale 2: 128x128, 4x4x48 = 768 tiles (scalar path) -------------
    for (int t = blockIdx.x; t < 768; t += nb) {
        int z = t >> 4, rem = t & 15;
        int by = rem >> 2, bx = rem & 3;
        scalar_tile(pa2 + (size_t)z * (128 * 128), pb2 + (size_t)z * (128 * 128),
                    128, 128, bx * 32, by * 32, z,
                    partial, 15360 + t, pa3, pb3, true, (float*)sm, red);
    }
    grid_sync(cnt, 3u * nb);

    // ---- scale 3: 64x64, 2x2x48 = 192 tiles -----------------------------
    for (int t = blockIdx.x; t < 192; t += nb) {
        int z = t >> 2, rem = t & 3;
        int by = rem >> 1, bx = rem & 1;
        scalar_tile(pa3 + (size_t)z * (64 * 64), pb3 + (size_t)z * (64 * 64),
                    64, 64, bx * 32, by * 32, z,
                    partial, 16128 + t, pa4, pb4, true, (float*)sm, red);
    }
    grid_sync(cnt, 4u * nb);

    // ---- scale 4: 32x32, 48 tiles, no pool ------------------------------
    for (int t = blockIdx.x; t < 48; t += nb) {
        scalar_tile(pa4 + (size_t)t * (32 * 32), pb4 + (size_t)t * (32 * 32),
                    32, 32, 0, 0, t,
                    partial, 16320 + t, nullptr, nullptr, false, (float*)sm, red);
    }
    grid_sync(cnt, 5u * nb);

    // ---- final combine (block 0) ----------------------------------------
    if (blockIdx.x == 0) final_reduce(partial, out, sm);
}

// ---------------------------------------------------------------------------
extern "C" void kernel_launch(void* const* d_in, const int* in_sizes, int n_in,
                              void* d_out, int out_size, void* d_ws, size_t ws_size,
                              hipStream_t stream) {
    (void)in_sizes; (void)n_in; (void)out_size; (void)ws_size;
    const float* A0 = (const float*)d_in[0];
    const float* B0 = (const float*)d_in[1];
    float* out = (float*)d_out;
    char* ws = (char*)d_ws;

    // Grid sized to guaranteed co-residency (deadlock-free grid barrier):
    // occupancy query once, cached. Expect 5 blocks/CU (LDS 27.9 KB) x 256 CU.
    static int nblk = 0;
    if (nblk == 0) {
        int bpc = 0;
        if (hipOccupancyMaxActiveBlocksPerMultiprocessor(&bpc, ms_ssim_fused,
                                                         256, 0) != hipSuccess ||
            bpc < 1)
            bpc = 2;                              // ultra-conservative fallback
        int cu = 256;
        hipDeviceProp_t prop;
        int dev = 0;
        if (hipGetDevice(&dev) == hipSuccess &&
            hipGetDeviceProperties(&prop, dev) == hipSuccess &&
            prop.multiProcessorCount > 0)
            cu = prop.multiProcessorCount;
        long nb = (long)bpc * (long)cu;
        if (nb > 12288) nb = 12288;
        nblk = (int)nb;
    }

    hipMemsetAsync(ws + CNT_OFF, 0, 64, stream);   // zero grid-barrier counter
    ms_ssim_fused<<<dim3(nblk), dim3(256), 0, stream>>>(A0, B0, ws, out);
}

// Round 2
// 417.126 us; speedup vs baseline: 1.1818x; 1.1818x over previous
//
#include <hip/hip_runtime.h>

#define HALO 10
#define NIMG 48                 // 16 batch * 3 channels

// Gaussian(sigma=1.5, 11 taps), normalized (computed offline in double).
#define GWLIST { 0.0010284f, 0.0075987f, 0.0360008f, 0.1093607f, 0.2130056f, \
                 0.2660117f, 0.2130056f, 0.1093607f, 0.0360008f, 0.0075987f, 0.0010284f }

// ---- MFMA-path LDS layout (fp16) -----------------------------------------
#define PP   56                 // stage-1 plane pitch (fp16 units)
#define PSZ  (48 * 56)          // plane size = 2688 fp16
#define HTP  56                 // h_T pitch along r (fp16 units)
#define HTSZ (32 * 56)          // per-quantity h_T = 1792 fp16
#define WT0  (5 * PSZ)          // wfrag table offset = 13440 (byte 26880)
#define LDSH (WT0 + 64 * 8)     // 13952 fp16 = 27904 B

// ---- scalar-path LDS layout (fp32), aliases bytes [0, 26880) of sm -------
#define TH   32
#define ROWS (TH + HALO)        // 42
#define HSTR 32
#define HQ   (ROWS * HSTR)      // 1344 floats

// ---- workspace layout -----------------------------------------------------
// [0, 130944)           : 16368 float2 partials
// [204800, 208896)      : grid-barrier state (16 arrive lines + 16 release
//                         lines, 128 B apart; memset to 0 each launch)
// [262144, ...)         : pyramid buffers
#define CNT_OFF (200 * 1024)
#define PYR_OFF (1 << 18)

typedef _Float16 half8 __attribute__((ext_vector_type(8)));
typedef _Float16 half4 __attribute__((ext_vector_type(4)));
typedef float    floatx4 __attribute__((ext_vector_type(4)));

// ---------------- device-scope grid barrier (monitor pattern) --------------
// R1 post-mortem: 1280 blocks polling ONE agent-scope address at s_sleep(8)
// (~6G polls/s) melted the coherence point (~400 us idle). Fix:
//   arrive : 16 striped counters (<=80 one-shot RMWs each, no hotspot)
//   monitor: block 0 thread 0 is the SOLE poller of arrive counters
//   release: 16 striped lines; each worker polls only line (bid&15) at
//            s_sleep(64) ~1.7us -> ~47M pipelined loads/s/line, no RMW.
// Epochs are monotonic (k-th barrier waits for release >= k), so no reset
// between barriers; state is memset once per launch.
__device__ __forceinline__ void grid_sync(char* bar, unsigned k, unsigned nb)
{
    __syncthreads();
    if (threadIdx.x == 0) {
        unsigned* arrive  = (unsigned*)bar;            // 16 lines x 32 dwords
        unsigned* release = (unsigned*)(bar + 2048);   // 16 lines x 32 dwords
        __threadfence();                               // release block's writes
        atomicAdd(&arrive[(blockIdx.x & 15) * 32], 1u);
        if (blockIdx.x == 0) {
            for (;;) {
                unsigned s = 0;
                #pragma unroll
                for (int i = 0; i < 16; ++i)
                    s += __hip_atomic_load(&arrive[i * 32], __ATOMIC_RELAXED,
                                           __HIP_MEMORY_SCOPE_AGENT);
                if (s >= k * nb) break;
                __builtin_amdgcn_s_sleep(32);          // ~0.85 us, sole poller
            }
            #pragma unroll
            for (int i = 0; i < 16; ++i)
                __hip_atomic_store(&release[i * 32], k, __ATOMIC_RELEASE,
                                   __HIP_MEMORY_SCOPE_AGENT);
        } else {
            const unsigned* myrel = &release[(blockIdx.x & 15) * 32];
            if (__hip_atomic_load(myrel, __ATOMIC_RELAXED,
                                  __HIP_MEMORY_SCOPE_AGENT) < k) {
                do {
                    __builtin_amdgcn_s_sleep(64);      // ~1.7 us between polls
                } while (__hip_atomic_load(myrel, __ATOMIC_RELAXED,
                                           __HIP_MEMORY_SCOPE_AGENT) < k);
            }
        }
        __threadfence();                               // acquire others' writes
    }
    __syncthreads();
}

// ======================= MFMA tile body (scales 0,1) =======================
// Identical math/order to the verified ssim_mfma_kernel (absmax 0.0).
// wfrag table is prebuilt once per block (persistent LDS).
__device__ __forceinline__ void mfma_tile(
    const float* __restrict__ a, const float* __restrict__ b,
    const int H, const int W, const int gx0, const int gy0, const int z,
    float2* __restrict__ partial, const int slot,
    float* __restrict__ poolA, float* __restrict__ poolB,
    _Float16* __restrict__ sm, float* __restrict__ red)
{
    const int tid  = threadIdx.x;
    const int lane = tid & 63;
    const int wv   = tid >> 6;

    // ---- stage 1: 48x48 region -> 5 fp16 quantity planes ----------------
    const bool fast = (gy0 + 48 <= H) && (gx0 + 48 <= W);
    for (int e = tid; e < 288; e += 256) {        // 48 rows x 6 col-octets
        int r = e / 6, c8 = e - r * 6;
        float fa[8], fb[8];
        if (fast) {
            const float* pa = a + (size_t)(gy0 + r) * W + gx0 + c8 * 8;
            const float* pb = b + (size_t)(gy0 + r) * W + gx0 + c8 * 8;
            *(float4*)&fa[0] = *(const float4*)pa;
            *(float4*)&fa[4] = *(const float4*)(pa + 4);
            *(float4*)&fb[0] = *(const float4*)pb;
            *(float4*)&fb[4] = *(const float4*)(pb + 4);
        } else {
            int gy = gy0 + r;
            #pragma unroll
            for (int i = 0; i < 8; ++i) {
                int gx = gx0 + c8 * 8 + i;
                bool ok = (gy < H) && (gx < W);
                size_t idx = (size_t)gy * W + gx;
                fa[i] = ok ? a[idx] : 0.f;
                fb[i] = ok ? b[idx] : 0.f;
            }
        }
        half8 ha, hb;
        #pragma unroll
        for (int i = 0; i < 8; ++i) {
            ha[i] = (_Float16)fa[i];
            hb[i] = (_Float16)fb[i];
        }
        half8 haa = ha * ha;
        half8 hbb = hb * hb;
        half8 hab = ha * hb;
        int o = r * PP + c8 * 8;
        *(half8*)&sm[o + 0 * PSZ] = ha;
        *(half8*)&sm[o + 1 * PSZ] = hb;
        *(half8*)&sm[o + 2 * PSZ] = haa;
        *(half8*)&sm[o + 3 * PSZ] = hbb;
        *(half8*)&sm[o + 4 * PSZ] = hab;
    }
    __syncthreads();

    const half8 wfrag = *(const half8*)&sm[WT0 + lane * 8];

    // ---- stage 2a: h-conv via MFMA, results held in registers -----------
    half4 res[8];
    {
        const int arow = (lane & 15) * PP + ((lane >> 4) << 3);
        #pragma unroll
        for (int u = 0; u < 8; ++u) {
            int jj = wv + 4 * u;
            if (jj < 30) {                        // wave-uniform
                int q = jj / 6, rem = jj - q * 6;
                int m0 = (rem >> 1) << 4;
                int x0 = (rem & 1) << 4;
                half8 afrag = *(const half8*)&sm[q * PSZ + m0 * PP + x0 + arow];
                floatx4 c = {0.f, 0.f, 0.f, 0.f};
                c = __builtin_amdgcn_mfma_f32_16x16x32_f16(afrag, wfrag, c, 0, 0, 0);
                half4 hv;
                hv[0] = (_Float16)c[0]; hv[1] = (_Float16)c[1];
                hv[2] = (_Float16)c[2]; hv[3] = (_Float16)c[3];
                res[u] = hv;
            }
        }
    }
    __syncthreads();      // all plane reads done; plane region now reusable

    // ---- stage 2b: write transposed fp16 h_T into (dead) plane region ---
    {
        const int crow = (lane & 15) * HTP + ((lane >> 4) << 2);
        #pragma unroll
        for (int u = 0; u < 8; ++u) {
            int jj = wv + 4 * u;
            if (jj < 30) {
                int q = jj / 6, rem = jj - q * 6;
                int m0 = (rem >> 1) << 4;
                int x0 = (rem & 1) << 4;
                *(half4*)&sm[q * HTSZ + x0 * HTP + m0 + crow] = res[u];
            }
        }
    }
    __syncthreads();

    // ---- stage 3: v-conv via MFMA + SSIM --------------------------------
    float csSum = 0.f, ssimSum = 0.f;
    {
        const int y0 = (wv >> 1) << 4;
        const int x0 = (wv & 1) << 4;
        const int brow = (lane & 15) * HTP + ((lane >> 4) << 3);
        floatx4 m[5];
        #pragma unroll
        for (int q = 0; q < 5; ++q) {
            half8 bfrag = *(const half8*)&sm[q * HTSZ + x0 * HTP + y0 + brow];
            floatx4 c = {0.f, 0.f, 0.f, 0.f};
            m[q] = __builtin_amdgcn_mfma_f32_16x16x32_f16(wfrag, bfrag, c, 0, 0, 0);
        }
        const int OH = H - HALO, OW = W - HALO;
        const int gx  = gx0 + x0 + (lane & 15);
        const int gyb = gy0 + y0 + ((lane >> 4) << 2);
        const float C1 = 1e-4f;   // (0.01*1)^2
        const float C2 = 9e-4f;   // (0.03*1)^2
        if (gx < OW) {
            #pragma unroll
            for (int i = 0; i < 4; ++i) {
                int gy = gyb + i;
                if (gy < OH) {
                    float mu1 = m[0][i], mu2 = m[1][i];
                    float s1sq = m[2][i] - mu1 * mu1;
                    float s2sq = m[3][i] - mu2 * mu2;
                    float s12  = m[4][i] - mu1 * mu2;
                    float denom = s1sq + s2sq + C2;
                    float num   = 2.f * s12 + C2;
                    float csv = num * __frcp_rn(denom);
                    float ssv = csv * (2.f * mu1 * mu2 + C1) *
                                __frcp_rn(mu1 * mu1 + mu2 * mu2 + C1);
                    csSum   += csv;
                    ssimSum += ssv;
                }
            }
        }
    }

    // ---- block reduction -> per-block partial slot ----------------------
    #pragma unroll
    for (int off = 32; off > 0; off >>= 1) {
        csSum   += __shfl_down(csSum, off, 64);
        ssimSum += __shfl_down(ssimSum, off, 64);
    }
    if (lane == 0) {
        red[wv]     = csSum;
        red[8 + wv] = ssimSum;
    }
    __syncthreads();
    if (tid == 0) {
        float c = 0.f, s = 0.f;
        #pragma unroll
        for (int i = 0; i < 4; ++i) { c += red[i]; s += red[8 + i]; }
        partial[slot] = make_float2(c, s);
    }

    // ---- fused 2x2 avg-pool of this block's own 32x32 input region ------
    if (tid < 128) {
        const int OH2 = H >> 1, OW2 = W >> 1;
        const int img = tid >> 6;            // 0 = A, 1 = B
        const int rem = tid & 63;
        const int pr  = rem >> 2;            // pooled row 0..15
        const int pq  = rem & 3;             // pooled float4-col 0..3
        const float* src = img ? b : a;
        float* dst = (img ? poolB : poolA) + (size_t)z * OH2 * OW2;
        size_t base = (size_t)(gy0 + 2 * pr) * W + gx0 + pq * 8;
        float4 r0 = *(const float4*)(src + base);
        float4 r1 = *(const float4*)(src + base + 4);
        float4 r2 = *(const float4*)(src + base + W);
        float4 r3 = *(const float4*)(src + base + W + 4);
        float4 o;
        o.x = 0.25f * (r0.x + r0.y + r2.x + r2.y);
        o.y = 0.25f * (r0.z + r0.w + r2.z + r2.w);
        o.z = 0.25f * (r1.x + r1.y + r3.x + r3.y);
        o.w = 0.25f * (r1.z + r1.w + r3.z + r3.w);
        *(float4*)(dst + (size_t)((gy0 >> 1) + pr) * OW2 + (gx0 >> 1) + pq * 4) = o;
    }
}

// ================= exact fp32 scalar tile body (scales 2-4) ================
__device__ __forceinline__ void scalar_tile(
    const float* __restrict__ a, const float* __restrict__ b,
    const int H, const int W, const int gx0, const int gy0, const int z,
    float2* __restrict__ partial, const int slot,
    float* __restrict__ poolA, float* __restrict__ poolB, const bool fuse,
    float* __restrict__ lds, float* __restrict__ red)
{
    const float w[11] = GWLIST;
    const int tid = threadIdx.x;

    const bool fast = (gy0 + ROWS <= H) && (gx0 + 44 <= W);
    for (int e = tid; e < ROWS * 8; e += 256) {
        int r = e >> 3, c0 = (e & 7) * 4;
        int gy = gy0 + r;
        float s1[4]  = {0.f, 0.f, 0.f, 0.f};
        float s2[4]  = {0.f, 0.f, 0.f, 0.f};
        float s11[4] = {0.f, 0.f, 0.f, 0.f};
        float s22[4] = {0.f, 0.f, 0.f, 0.f};
        float s12[4] = {0.f, 0.f, 0.f, 0.f};
        #pragma unroll
        for (int c = 0; c < 4; ++c) {
            float ea[4], eb[4];
            if (fast) {
                const float* pa = a + (size_t)gy * W + gx0 + c0 + 4 * c;
                const float* pb = b + (size_t)gy * W + gx0 + c0 + 4 * c;
                *(float4*)&ea[0] = *(const float4*)pa;
                *(float4*)&eb[0] = *(const float4*)pb;
            } else {
                #pragma unroll
                for (int t = 0; t < 4; ++t) {
                    int gx = gx0 + c0 + 4 * c + t;
                    bool ok = (gy < H) && (gx < W);
                    size_t idx = (size_t)gy * W + gx;
                    ea[t] = ok ? a[idx] : 0.f;
                    eb[t] = ok ? b[idx] : 0.f;
                }
            }
            #pragma unroll
            for (int mm = 0; mm < 4; ++mm) {
                const int i = 4 * c + mm;
                float va = ea[mm], vb = eb[mm];
                float vaa = va * va, vbb = vb * vb, vab = va * vb;
                #pragma unroll
                for (int k = 0; k < 4; ++k) {
                    const int j = i - k;
                    if (j >= 0 && j <= 10) {
                        float wj = w[j];
                        s1[k]  += wj * va;
                        s2[k]  += wj * vb;
                        s11[k] += wj * vaa;
                        s22[k] += wj * vbb;
                        s12[k] += wj * vab;
                    }
                }
            }
        }
        int hb = r * HSTR + c0;
        *(float4*)&lds[hb + 0 * HQ] = make_float4(s1[0],  s1[1],  s1[2],  s1[3]);
        *(float4*)&lds[hb + 1 * HQ] = make_float4(s2[0],  s2[1],  s2[2],  s2[3]);
        *(float4*)&lds[hb + 2 * HQ] = make_float4(s11[0], s11[1], s11[2], s11[3]);
        *(float4*)&lds[hb + 3 * HQ] = make_float4(s22[0], s22[1], s22[2], s22[3]);
        *(float4*)&lds[hb + 4 * HQ] = make_float4(s12[0], s12[1], s12[2], s12[3]);
    }
    __syncthreads();

    const float C1 = 1e-4f;
    const float C2 = 9e-4f;
    float csSum = 0.f, ssimSum = 0.f;
    {
        const int ox  = tid & 31;
        const int oy0 = (tid >> 5) * 4;
        float m[5][4];
        #pragma unroll
        for (int q = 0; q < 5; ++q) {
            const float* hq = &lds[q * HQ + oy0 * HSTR + ox];
            float win[14];
            #pragma unroll
            for (int i = 0; i < 14; ++i) win[i] = hq[i * HSTR];
            #pragma unroll
            for (int k = 0; k < 4; ++k) {
                float acc = 0.f;
                #pragma unroll
                for (int j = 0; j < 11; ++j) acc += w[j] * win[k + j];
                m[q][k] = acc;
            }
        }
        const int OH = H - HALO, OW = W - HALO;
        const int gx = gx0 + ox;
        #pragma unroll
        for (int k = 0; k < 4; ++k) {
            int gy = gy0 + oy0 + k;
            if (gy < OH && gx < OW) {
                float mu1 = m[0][k], mu2 = m[1][k];
                float s1sq = m[2][k] - mu1 * mu1;
                float s2sq = m[3][k] - mu2 * mu2;
                float s12  = m[4][k] - mu1 * mu2;
                float denom  = s1sq + s2sq + C2;
                float num_cs = 2.f * s12 + C2;
                float csv = num_cs * __frcp_rn(denom);
                float ssv = csv * (2.f * mu1 * mu2 + C1) *
                            __frcp_rn(mu1 * mu1 + mu2 * mu2 + C1);
                csSum   += csv;
                ssimSum += ssv;
            }
        }
    }

    #pragma unroll
    for (int off = 32; off > 0; off >>= 1) {
        csSum   += __shfl_down(csSum, off, 64);
        ssimSum += __shfl_down(ssimSum, off, 64);
    }
    int wave = tid >> 6, lane = tid & 63;
    if (lane == 0) {
        red[wave]     = csSum;
        red[8 + wave] = ssimSum;
    }
    __syncthreads();
    if (tid == 0) {
        float c = 0.f, s = 0.f;
        #pragma unroll
        for (int i = 0; i < 4; ++i) { c += red[i]; s += red[8 + i]; }
        partial[slot] = make_float2(c, s);
    }

    if (fuse && tid < 128) {
        const int OH2 = H >> 1, OW2 = W >> 1;
        const int img = tid >> 6;
        const int rem = tid & 63;
        const int pr  = rem >> 2;
        const int pq  = rem & 3;
        const float* src = img ? b : a;
        float* dst = (img ? poolB : poolA) + (size_t)z * OH2 * OW2;
        size_t base = (size_t)(gy0 + 2 * pr) * W + gx0 + pq * 8;
        float4 r0 = *(const float4*)(src + base);
        float4 r1 = *(const float4*)(src + base + 4);
        float4 r2 = *(const float4*)(src + base + W);
        float4 r3 = *(const float4*)(src + base + W + 4);
        float4 o;
        o.x = 0.25f * (r0.x + r0.y + r2.x + r2.y);
        o.y = 0.25f * (r0.z + r0.w + r2.z + r2.w);
        o.z = 0.25f * (r1.x + r1.y + r3.x + r3.y);
        o.w = 0.25f * (r1.z + r1.w + r3.z + r3.w);
        *(float4*)(dst + (size_t)((gy0 >> 1) + pr) * OW2 + (gx0 >> 1) + pq * 4) = o;
    }
}

// ---------------- final reduction (block 0 only) ---------------------------
__device__ __forceinline__ void final_reduce(const float2* __restrict__ partial,
                                             float* __restrict__ out,
                                             _Float16* __restrict__ smraw)
{
    double* dred = (double*)smraw;       // 8 doubles
    double* resC = dred + 8;             // 5
    double* resS = dred + 13;            // 5
    const int segs[6] = {0, 12288, 15360, 16128, 16320, 16368};
    const int tid = threadIdx.x;
    for (int s = 0; s < 5; ++s) {
        double c = 0.0, v = 0.0;
        #pragma unroll 4
        for (int i = segs[s] + tid; i < segs[s + 1]; i += 256) {
            float2 p = partial[i];
            c += (double)p.x;
            v += (double)p.y;
        }
        #pragma unroll
        for (int off = 32; off > 0; off >>= 1) {
            c += __shfl_down(c, off, 64);
            v += __shfl_down(v, off, 64);
        }
        int wave = tid >> 6, lane = tid & 63;
        __syncthreads();
        if (lane == 0) { dred[wave] = c; dred[4 + wave] = v; }
        __syncthreads();
        if (tid == 0) {
            resC[s] = dred[0] + dred[1] + dred[2] + dred[3];
            resS[s] = dred[4] + dred[5] + dred[6] + dred[7];
        }
    }
    __syncthreads();
    if (tid == 0) {
        const double wgt[5] = {0.0448, 0.2856, 0.3001, 0.2363, 0.1333};
        double ms = 1.0;
        for (int s = 0; s < 5; ++s) {
            int Hs = 512 >> s;
            double cnt = (double)NIMG * (double)(Hs - 10) * (double)(Hs - 10);
            double cs = resC[s] / cnt;
            double sv = resS[s] / cnt;
            if (cs < 0.0) cs = 0.0;
            if (sv < 0.0) sv = 0.0;
            cs = (cs + 1.0) * 0.5;
            sv = (sv + 1.0) * 0.5;
            ms *= pow((s < 4) ? cs : sv, wgt[s]);
        }
        out[0] = (float)(1.0 - ms);
    }
}

// ===================== single persistent fused kernel ======================
__global__ __launch_bounds__(256, 5) void ms_ssim_fused(
    const float* __restrict__ A0, const float* __restrict__ B0,
    char* __restrict__ ws, float* __restrict__ out)
{
    __shared__ __align__(16) _Float16 sm[LDSH];   // 27904 B (scalar path aliases [0,26880) as fp32)
    __shared__ float red[16];

    float2* partial = (float2*)ws;
    float*  pyr     = (float*)(ws + PYR_OFF);
    char*   bar     = ws + CNT_OFF;

    const size_t n1 = (size_t)NIMG * 256 * 256;
    const size_t n2 = (size_t)NIMG * 128 * 128;
    const size_t n3 = (size_t)NIMG * 64 * 64;
    float* pa1 = pyr;        float* pb1 = pa1 + n1;
    float* pa2 = pb1 + n1;   float* pb2 = pa2 + n2;
    float* pa3 = pb2 + n2;   float* pb3 = pa3 + n3;
    float* pa4 = pb3 + n3;   float* pb4 = pa4 + (size_t)NIMG * 32 * 32;

    // ---- wave 0: build band-weight fragment table ONCE per block --------
    if (threadIdx.x < 64) {
        const float w[11] = GWLIST;
        int base = ((threadIdx.x >> 4) << 3) - (threadIdx.x & 15);
        half8 wf;
        #pragma unroll
        for (int i = 0; i < 8; ++i) {
            int j = base + i;
            float v = 0.f;
            #pragma unroll
            for (int J = 0; J < 11; ++J) v = (j == J) ? w[J] : v;
            wf[i] = (_Float16)v;
        }
        *(half8*)&sm[WT0 + threadIdx.x * 8] = wf;
    }

    const int nb = (int)gridDim.x;

    // ---- scale 0: 512x512, 16x16x48 = 12288 tiles (MFMA path) -----------
    for (int t = blockIdx.x; t < 12288; t += nb) {
        int z = t >> 8, rem = t & 255;
        int by = rem >> 4, bx = rem & 15;
        mfma_tile(A0 + (size_t)z * (512 * 512), B0 + (size_t)z * (512 * 512),
                  512, 512, bx * 32, by * 32, z,
                  partial, t, pa1, pb1, sm, red);
    }
    grid_sync(bar, 1u, nb);

    // ---- scale 1: 256x256, 8x8x48 = 3072 tiles (MFMA path) --------------
    for (int t = blockIdx.x; t < 3072; t += nb) {
        int z = t >> 6, rem = t & 63;
        int by = rem >> 3, bx = rem & 7;
        mfma_tile(pa1 + (size_t)z * (256 * 256), pb1 + (size_t)z * (256 * 256),
                  256, 256, bx * 32, by * 32, z,
                  partial, 12288 + t, pa2, pb2, sm, red);
    }
    grid_sync(bar, 2u, nb);

    // ---- scale 2: 128x128, 4x4x48 = 768 tiles (scalar path) -------------
    for (int t = blockIdx.x; t < 768; t += nb) {
        int z = t >> 4, rem = t & 15;
        int by = rem >> 2, bx = rem & 3;
        scalar_tile(pa2 + (size_t)z * (128 * 128), pb2 + (size_t)z * (128 * 128),
                    128, 128, bx * 32, by * 32, z,
                    partial, 15360 + t, pa3, pb3, true, (float*)sm, red);
    }
    grid_sync(bar, 3u, nb);

    // ---- scale 3: 64x64, 2x2x48 = 192 tiles -----------------------------
    for (int t = blockIdx.x; t < 192; t += nb) {
        int z = t >> 2, rem = t & 3;
        int by = rem >> 1, bx = rem & 1;
        scalar_tile(pa3 + (size_t)z * (64 * 64), pb3 + (size_t)z * (64 * 64),
                    64, 64, bx * 32, by * 32, z,
                    partial, 16128 + t, pa4, pb4, true, (float*)sm, red);
    }
    grid_sync(bar, 4u, nb);

    // ---- scale 4: 32x32, 48 tiles, no pool ------------------------------
    for (int t = blockIdx.x; t < 48; t += nb) {
        scalar_tile(pa4 + (size_t)t * (32 * 32), pb4 + (size_t)t * (32 * 32),
                    32, 32, 0, 0, t,
                    partial, 16320 + t, nullptr, nullptr, false, (float*)sm, red);
    }
    grid_sync(bar, 5u, nb);

    // ---- final combine (block 0) ----------------------------------------
    if (blockIdx.x == 0) final_reduce(partial, out, sm);
}

// ---------------------------------------------------------------------------
extern "C" void kernel_launch(void* const* d_in, const int* in_sizes, int n_in,
                              void* d_out, int out_size, void* d_ws, size_t ws_size,
                              hipStream_t stream) {
    (void)in_sizes; (void)n_in; (void)out_size; (void)ws_size;
    const float* A0 = (const float*)d_in[0];
    const float* B0 = (const float*)d_in[1];
    float* out = (float*)d_out;
    char* ws = (char*)d_ws;

    // Grid sized to guaranteed co-residency (deadlock-free grid barrier):
    // occupancy query once, cached. Expect 5 blocks/CU (LDS 27.9 KB) x 256 CU.
    static int nblk = 0;
    if (nblk == 0) {
        int bpc = 0;
        if (hipOccupancyMaxActiveBlocksPerMultiprocessor(&bpc, ms_ssim_fused,
                                                         256, 0) != hipSuccess ||
            bpc < 1)
            bpc = 2;                              // ultra-conservative fallback
        int cu = 256;
        hipDeviceProp_t prop;
        int dev = 0;
        if (hipGetDevice(&dev) == hipSuccess &&
            hipGetDeviceProperties(&prop, dev) == hipSuccess &&
            prop.multiProcessorCount > 0)
            cu = prop.multiProcessorCount;
        long nb = (long)bpc * (long)cu;
        if (nb > 12288) nb = 12288;
        nblk = (int)nb;
    }

    hipMemsetAsync(ws + CNT_OFF, 0, 4096, stream);   // zero barrier state
    ms_ssim_fused<<<dim3(nblk), dim3(256), 0, stream>>>(A0, B0, ws, out);
}

// Round 4
// 312.385 us; speedup vs baseline: 1.5781x; 1.3353x over previous
//
#include <hip/hip_runtime.h>

#define HALO 10
#define NIMG 48                 // 16 batch * 3 channels

// Gaussian(sigma=1.5, 11 taps), normalized (computed offline in double).
#define GWLIST { 0.0010284f, 0.0075987f, 0.0360008f, 0.1093607f, 0.2130056f, \
                 0.2660117f, 0.2130056f, 0.1093607f, 0.0360008f, 0.0075987f, 0.0010284f }

// ---- MFMA-path LDS layout (fp16) -----------------------------------------
#define PP   56                 // stage-1 plane pitch (fp16 units)
#define PSZ  (48 * 56)          // plane size = 2688 fp16
#define HTP  56                 // h_T pitch along r (fp16 units)
#define HTSZ (32 * 56)          // per-quantity h_T = 1792 fp16
#define WT0  (5 * PSZ)          // wfrag table offset = 13440 (byte 26880)
#define LDSH (WT0 + 64 * 8)     // 13952 fp16 = 27904 B

// ---- scalar-path LDS layout (fp32), aliases bytes [0, 26880) of sm -------
#define TH   32
#define ROWS (TH + HALO)        // 42
#define HSTR 32
#define HQ   (ROWS * HSTR)      // 1344 floats

// ---- workspace layout -----------------------------------------------------
// [0, 130944)           : 16368 float2 partials (sc1-written)
// [204800, 208896)      : grid-barrier state (16 arrive + 16 release lines,
//                         128 B apart; memset to 0 each launch)
// [262144, ...)         : pyramid buffers (sc1-written)
#define CNT_OFF (200 * 1024)
#define PYR_OFF (1 << 18)

// Spin watchdog: wall_clock64 ticks at a constant ~100 MHz. 20M ticks ~ 200ms
// >> any legitimate wait (<1 ms), << container watchdog. On trip, fall
// through: a broken barrier then yields a VISIBLE wrong answer, not a hang.
#define SPIN_TIMEOUT 20000000ull

typedef _Float16 half8 __attribute__((ext_vector_type(8)));
typedef _Float16 half4 __attribute__((ext_vector_type(4)));
typedef float    floatx4 __attribute__((ext_vector_type(4)));

// ---- device-coherent (sc1) stores: write through to the MALL --------------
// All data that crosses a grid barrier goes through these, so the barrier
// needs NO per-block agent fences (R2 post-mortem: 2x1280 buffer_wbl2/inv L2
// walks per barrier ~ 85 us each; 5 barriers ~ the 420 us idle residual).
// Readers use plain loads: these lines are never normal-written or pre-read
// within a launch, and kernel-dispatch acquire invalidates the XCD L2s, so
// the first read misses to the MALL and caches the current value.
__device__ __forceinline__ void store_f2_sc1(float2* p, float2 v) {
    union { float2 f; unsigned long long u; } cv; cv.f = v;
    __hip_atomic_store((unsigned long long*)p, cv.u,
                       __ATOMIC_RELAXED, __HIP_MEMORY_SCOPE_AGENT);
}
__device__ __forceinline__ void store_f4_sc1(float* p, float4 v) {
    union { float4 f; unsigned long long u[2]; } cv; cv.f = v;
    unsigned long long* q = (unsigned long long*)p;
    __hip_atomic_store(q,     cv.u[0], __ATOMIC_RELAXED, __HIP_MEMORY_SCOPE_AGENT);
    __hip_atomic_store(q + 1, cv.u[1], __ATOMIC_RELAXED, __HIP_MEMORY_SCOPE_AGENT);
}

// ---------------- device-scope grid barrier (monitor, fence-light) ---------
//   arrive : 16 striped counters, relaxed agent RMW (stores already drained
//            by __syncthreads' vmcnt(0); sc1 data is at the MALL).
//   monitor: block 0 thread 0 is the SOLE poller of arrive counters.
//   release: RELEASE-store (one wbl2 from ONE thread per barrier — 5 total,
//            vs R2's 12800 per-block fence walks).
//   workers: poll only line (bid&15), relaxed agent loads, s_sleep paced.
// Epochs monotonic (k-th barrier waits for release >= k); no reset between
// barriers; state memset once per launch. Both spins carry a watchdog.
__device__ __forceinline__ void grid_sync(char* bar, unsigned k, unsigned nb)
{
    __syncthreads();
    if (threadIdx.x == 0) {
        unsigned* arrive  = (unsigned*)bar;            // 16 lines x 32 dwords
        unsigned* release = (unsigned*)(bar + 2048);   // 16 lines x 32 dwords
        __hip_atomic_fetch_add(&arrive[(blockIdx.x & 15) * 32], 1u,
                               __ATOMIC_RELAXED, __HIP_MEMORY_SCOPE_AGENT);
        if (blockIdx.x == 0) {
            unsigned long long t0 = wall_clock64();
            for (;;) {
                unsigned s = 0;
                #pragma unroll
                for (int i = 0; i < 16; ++i)
                    s += __hip_atomic_load(&arrive[i * 32], __ATOMIC_RELAXED,
                                           __HIP_MEMORY_SCOPE_AGENT);
                if (s >= k * nb) break;
                if (wall_clock64() - t0 > SPIN_TIMEOUT) break;   // watchdog
                __builtin_amdgcn_s_sleep(16);          // ~0.43 us, sole poller
            }
            #pragma unroll
            for (int i = 0; i < 16; ++i)
                __hip_atomic_store(&release[i * 32], k, __ATOMIC_RELEASE,
                                   __HIP_MEMORY_SCOPE_AGENT);
        } else {
            unsigned* myrel = &release[(blockIdx.x & 15) * 32];
            if (__hip_atomic_load(myrel, __ATOMIC_RELAXED,
                                  __HIP_MEMORY_SCOPE_AGENT) < k) {
                unsigned long long t0 = wall_clock64();
                do {
                    if (wall_clock64() - t0 > SPIN_TIMEOUT) break;  // watchdog
                    __builtin_amdgcn_s_sleep(32);      // ~0.85 us between polls
                } while (__hip_atomic_load(myrel, __ATOMIC_RELAXED,
                                           __HIP_MEMORY_SCOPE_AGENT) < k);
            }
        }
    }
    __syncthreads();
}

// ======================= MFMA tile body (scales 0,1) =======================
// Identical math/order to the verified ssim_mfma_kernel (absmax 0.0).
// wfrag table is prebuilt once per block (persistent LDS).
__device__ __forceinline__ void mfma_tile(
    const float* __restrict__ a, const float* __restrict__ b,
    const int H, const int W, const int gx0, const int gy0, const int z,
    float2* __restrict__ partial, const int slot,
    float* __restrict__ poolA, float* __restrict__ poolB,
    _Float16* __restrict__ sm, float* __restrict__ red)
{
    const int tid  = threadIdx.x;
    const int lane = tid & 63;
    const int wv   = tid >> 6;

    // ---- stage 1: 48x48 region -> 5 fp16 quantity planes ----------------
    const bool fast = (gy0 + 48 <= H) && (gx0 + 48 <= W);
    for (int e = tid; e < 288; e += 256) {        // 48 rows x 6 col-octets
        int r = e / 6, c8 = e - r * 6;
        float fa[8], fb[8];
        if (fast) {
            const float* pa = a + (size_t)(gy0 + r) * W + gx0 + c8 * 8;
            const float* pb = b + (size_t)(gy0 + r) * W + gx0 + c8 * 8;
            *(float4*)&fa[0] = *(const float4*)pa;
            *(float4*)&fa[4] = *(const float4*)(pa + 4);
            *(float4*)&fb[0] = *(const float4*)pb;
            *(float4*)&fb[4] = *(const float4*)(pb + 4);
        } else {
            int gy = gy0 + r;
            #pragma unroll
            for (int i = 0; i < 8; ++i) {
                int gx = gx0 + c8 * 8 + i;
                bool ok = (gy < H) && (gx < W);
                size_t idx = (size_t)gy * W + gx;
                fa[i] = ok ? a[idx] : 0.f;
                fb[i] = ok ? b[idx] : 0.f;
            }
        }
        half8 ha, hb;
        #pragma unroll
        for (int i = 0; i < 8; ++i) {
            ha[i] = (_Float16)fa[i];
            hb[i] = (_Float16)fb[i];
        }
        half8 haa = ha * ha;
        half8 hbb = hb * hb;
        half8 hab = ha * hb;
        int o = r * PP + c8 * 8;
        *(half8*)&sm[o + 0 * PSZ] = ha;
        *(half8*)&sm[o + 1 * PSZ] = hb;
        *(half8*)&sm[o + 2 * PSZ] = haa;
        *(half8*)&sm[o + 3 * PSZ] = hbb;
        *(half8*)&sm[o + 4 * PSZ] = hab;
    }
    __syncthreads();

    const half8 wfrag = *(const half8*)&sm[WT0 + lane * 8];

    // ---- stage 2a: h-conv via MFMA, results held in registers -----------
    half4 res[8];
    {
        const int arow = (lane & 15) * PP + ((lane >> 4) << 3);
        #pragma unroll
        for (int u = 0; u < 8; ++u) {
            int jj = wv + 4 * u;
            if (jj < 30) {                        // wave-uniform
                int q = jj / 6, rem = jj - q * 6;
                int m0 = (rem >> 1) << 4;
                int x0 = (rem & 1) << 4;
                half8 afrag = *(const half8*)&sm[q * PSZ + m0 * PP + x0 + arow];
                floatx4 c = {0.f, 0.f, 0.f, 0.f};
                c = __builtin_amdgcn_mfma_f32_16x16x32_f16(afrag, wfrag, c, 0, 0, 0);
                half4 hv;
                hv[0] = (_Float16)c[0]; hv[1] = (_Float16)c[1];
                hv[2] = (_Float16)c[2]; hv[3] = (_Float16)c[3];
                res[u] = hv;
            }
        }
    }
    __syncthreads();      // all plane reads done; plane region now reusable

    // ---- stage 2b: write transposed fp16 h_T into (dead) plane region ---
    {
        const int crow = (lane & 15) * HTP + ((lane >> 4) << 2);
        #pragma unroll
        for (int u = 0; u < 8; ++u) {
            int jj = wv + 4 * u;
            if (jj < 30) {
                int q = jj / 6, rem = jj - q * 6;
                int m0 = (rem >> 1) << 4;
                int x0 = (rem & 1) << 4;
                *(half4*)&sm[q * HTSZ + x0 * HTP + m0 + crow] = res[u];
            }
        }
    }
    __syncthreads();

    // ---- stage 3: v-conv via MFMA (one 16x16 subtile per wave) + SSIM ---
    float csSum = 0.f, ssimSum = 0.f;
    {
        const int y0 = (wv >> 1) << 4;
        const int x0 = (wv & 1) << 4;
        const int brow = (lane & 15) * HTP + ((lane >> 4) << 3);
        floatx4 m[5];
        #pragma unroll
        for (int q = 0; q < 5; ++q) {
            half8 bfrag = *(const half8*)&sm[q * HTSZ + x0 * HTP + y0 + brow];
            floatx4 c = {0.f, 0.f, 0.f, 0.f};
            m[q] = __builtin_amdgcn_mfma_f32_16x16x32_f16(wfrag, bfrag, c, 0, 0, 0);
        }
        const int OH = H - HALO, OW = W - HALO;
        const int gx  = gx0 + x0 + (lane & 15);
        const int gyb = gy0 + y0 + ((lane >> 4) << 2);
        const float C1 = 1e-4f;   // (0.01*1)^2
        const float C2 = 9e-4f;   // (0.03*1)^2
        if (gx < OW) {
            #pragma unroll
            for (int i = 0; i < 4; ++i) {
                int gy = gyb + i;
                if (gy < OH) {
                    float mu1 = m[0][i], mu2 = m[1][i];
                    float s1sq = m[2][i] - mu1 * mu1;
                    float s2sq = m[3][i] - mu2 * mu2;
                    float s12  = m[4][i] - mu1 * mu2;
                    float denom = s1sq + s2sq + C2;
                    float num   = 2.f * s12 + C2;
                    float csv = num * __frcp_rn(denom);
                    float ssv = csv * (2.f * mu1 * mu2 + C1) *
                                __frcp_rn(mu1 * mu1 + mu2 * mu2 + C1);
                    csSum   += csv;
                    ssimSum += ssv;
                }
            }
        }
    }

    // ---- block reduction -> per-block partial slot ----------------------
    #pragma unroll
    for (int off = 32; off > 0; off >>= 1) {
        csSum   += __shfl_down(csSum, off, 64);
        ssimSum += __shfl_down(ssimSum, off, 64);
    }
    if (lane == 0) {
        red[wv]     = csSum;
        red[8 + wv] = ssimSum;
    }
    __syncthreads();
    if (tid == 0) {
        float c = 0.f, s = 0.f;
        #pragma unroll
        for (int i = 0; i < 4; ++i) { c += red[i]; s += red[8 + i]; }
        store_f2_sc1(&partial[slot], make_float2(c, s));
    }

    // ---- fused 2x2 avg-pool of this block's own 32x32 input region ------
    if (tid < 128) {
        const int OH2 = H >> 1, OW2 = W >> 1;
        const int img = tid >> 6;            // 0 = A, 1 = B
        const int rem = tid & 63;
        const int pr  = rem >> 2;            // pooled row 0..15
        const int pq  = rem & 3;             // pooled float4-col 0..3
        const float* src = img ? b : a;
        float* dst = (img ? poolB : poolA) + (size_t)z * OH2 * OW2;
        size_t base = (size_t)(gy0 + 2 * pr) * W + gx0 + pq * 8;
        float4 r0 = *(const float4*)(src + base);
        float4 r1 = *(const float4*)(src + base + 4);
        float4 r2 = *(const float4*)(src + base + W);
        float4 r3 = *(const float4*)(src + base + W + 4);
        float4 o;
        o.x = 0.25f * (r0.x + r0.y + r2.x + r2.y);
        o.y = 0.25f * (r0.z + r0.w + r2.z + r2.w);
        o.z = 0.25f * (r1.x + r1.y + r3.x + r3.y);
        o.w = 0.25f * (r1.z + r1.w + r3.z + r3.w);
        store_f4_sc1(dst + (size_t)((gy0 >> 1) + pr) * OW2 + (gx0 >> 1) + pq * 4, o);
    }
}

// ================= exact fp32 scalar tile body (scales 2-4) ================
__device__ __forceinline__ void scalar_tile(
    const float* __restrict__ a, const float* __restrict__ b,
    const int H, const int W, const int gx0, const int gy0, const int z,
    float2* __restrict__ partial, const int slot,
    float* __restrict__ poolA, float* __restrict__ poolB, const bool fuse,
    float* __restrict__ lds, float* __restrict__ red)
{
    const float w[11] = GWLIST;
    const int tid = threadIdx.x;

    const bool fast = (gy0 + ROWS <= H) && (gx0 + 44 <= W);
    for (int e = tid; e < ROWS * 8; e += 256) {
        int r = e >> 3, c0 = (e & 7) * 4;
        int gy = gy0 + r;
        float s1[4]  = {0.f, 0.f, 0.f, 0.f};
        float s2[4]  = {0.f, 0.f, 0.f, 0.f};
        float s11[4] = {0.f, 0.f, 0.f, 0.f};
        float s22[4] = {0.f, 0.f, 0.f, 0.f};
        float s12[4] = {0.f, 0.f, 0.f, 0.f};
        #pragma unroll
        for (int c = 0; c < 4; ++c) {
            float ea[4], eb[4];
            if (fast) {
                const float* pa = a + (size_t)gy * W + gx0 + c0 + 4 * c;
                const float* pb = b + (size_t)gy * W + gx0 + c0 + 4 * c;
                *(float4*)&ea[0] = *(const float4*)pa;
                *(float4*)&eb[0] = *(const float4*)pb;
            } else {
                #pragma unroll
                for (int t = 0; t < 4; ++t) {
                    int gx = gx0 + c0 + 4 * c + t;
                    bool ok = (gy < H) && (gx < W);
                    size_t idx = (size_t)gy * W + gx;
                    ea[t] = ok ? a[idx] : 0.f;
                    eb[t] = ok ? b[idx] : 0.f;
                }
            }
            #pragma unroll
            for (int mm = 0; mm < 4; ++mm) {
                const int i = 4 * c + mm;
                float va = ea[mm], vb = eb[mm];
                float vaa = va * va, vbb = vb * vb, vab = va * vb;
                #pragma unroll
                for (int k = 0; k < 4; ++k) {
                    const int j = i - k;
                    if (j >= 0 && j <= 10) {
                        float wj = w[j];
                        s1[k]  += wj * va;
                        s2[k]  += wj * vb;
                        s11[k] += wj * vaa;
                        s22[k] += wj * vbb;
                        s12[k] += wj * vab;
                    }
                }
            }
        }
        int hb = r * HSTR + c0;
        *(float4*)&lds[hb + 0 * HQ] = make_float4(s1[0],  s1[1],  s1[2],  s1[3]);
        *(float4*)&lds[hb + 1 * HQ] = make_float4(s2[0],  s2[1],  s2[2],  s2[3]);
        *(float4*)&lds[hb + 2 * HQ] = make_float4(s11[0], s11[1], s11[2], s11[3]);
        *(float4*)&lds[hb + 3 * HQ] = make_float4(s22[0], s22[1], s22[2], s22[3]);
        *(float4*)&lds[hb + 4 * HQ] = make_float4(s12[0], s12[1], s12[2], s12[3]);
    }
    __syncthreads();

    const float C1 = 1e-4f;
    const float C2 = 9e-4f;
    float csSum = 0.f, ssimSum = 0.f;
    {
        const int ox  = tid & 31;
        const int oy0 = (tid >> 5) * 4;
        float m[5][4];
        #pragma unroll
        for (int q = 0; q < 5; ++q) {
            const float* hq = &lds[q * HQ + oy0 * HSTR + ox];
            float win[14];
            #pragma unroll
            for (int i = 0; i < 14; ++i) win[i] = hq[i * HSTR];
            #pragma unroll
            for (int k = 0; k < 4; ++k) {
                float acc = 0.f;
                #pragma unroll
                for (int j = 0; j < 11; ++j) acc += w[j] * win[k + j];
                m[q][k] = acc;
            }
        }
        const int OH = H - HALO, OW = W - HALO;
        const int gx = gx0 + ox;
        #pragma unroll
        for (int k = 0; k < 4; ++k) {
            int gy = gy0 + oy0 + k;
            if (gy < OH && gx < OW) {
                float mu1 = m[0][k], mu2 = m[1][k];
                float s1sq = m[2][k] - mu1 * mu1;
                float s2sq = m[3][k] - mu2 * mu2;
                float s12  = m[4][k] - mu1 * mu2;
                float denom  = s1sq + s2sq + C2;
                float num_cs = 2.f * s12 + C2;
                float csv = num_cs * __frcp_rn(denom);
                float ssv = csv * (2.f * mu1 * mu2 + C1) *
                            __frcp_rn(mu1 * mu1 + mu2 * mu2 + C1);
                csSum   += csv;
                ssimSum += ssv;
            }
        }
    }

    #pragma unroll
    for (int off = 32; off > 0; off >>= 1) {
        csSum   += __shfl_down(csSum, off, 64);
        ssimSum += __shfl_down(ssimSum, off, 64);
    }
    int wave = tid >> 6, lane = tid & 63;
    if (lane == 0) {
        red[wave]     = csSum;
        red[8 + wave] = ssimSum;
    }
    __syncthreads();
    if (tid == 0) {
        float c = 0.f, s = 0.f;
        #pragma unroll
        for (int i = 0; i < 4; ++i) { c += red[i]; s += red[8 + i]; }
        store_f2_sc1(&partial[slot], make_float2(c, s));
    }

    if (fuse && tid < 128) {
        const int OH2 = H >> 1, OW2 = W >> 1;
        const int img = tid >> 6;
        const int rem = tid & 63;
        const int pr  = rem >> 2;
        const int pq  = rem & 3;
        const float* src = img ? b : a;
        float* dst = (img ? poolB : poolA) + (size_t)z * OH2 * OW2;
        size_t base = (size_t)(gy0 + 2 * pr) * W + gx0 + pq * 8;
        float4 r0 = *(const float4*)(src + base);
        float4 r1 = *(const float4*)(src + base + 4);
        float4 r2 = *(const float4*)(src + base + W);
        float4 r3 = *(const float4*)(src + base + W + 4);
        float4 o;
        o.x = 0.25f * (r0.x + r0.y + r2.x + r2.y);
        o.y = 0.25f * (r0.z + r0.w + r2.z + r2.w);
        o.z = 0.25f * (r1.x + r1.y + r3.x + r3.y);
        o.w = 0.25f * (r1.z + r1.w + r3.z + r3.w);
        store_f4_sc1(dst + (size_t)((gy0 >> 1) + pr) * OW2 + (gx0 >> 1) + pq * 4, o);
    }
}

// ---------------- final reduction (block 0 only) ---------------------------
__device__ __forceinline__ void final_reduce(const float2* __restrict__ partial,
                                             float* __restrict__ out,
                                             _Float16* __restrict__ smraw)
{
    double* dred = (double*)smraw;       // 8 doubles
    double* resC = dred + 8;             // 5
    double* resS = dred + 13;            // 5
    const int segs[6] = {0, 12288, 15360, 16128, 16320, 16368};
    const int tid = threadIdx.x;
    for (int s = 0; s < 5; ++s) {
        double c = 0.0, v = 0.0;
        #pragma unroll 4
        for (int i = segs[s] + tid; i < segs[s + 1]; i += 256) {
            float2 p = partial[i];
            c += (double)p.x;
            v += (double)p.y;
        }
        #pragma unroll
        for (int off = 32; off > 0; off >>= 1) {
            c += __shfl_down(c, off, 64);
            v += __shfl_down(v, off, 64);
        }
        int wave = tid >> 6, lane = tid & 63;
        __syncthreads();
        if (lane == 0) { dred[wave] = c; dred[4 + wave] = v; }
        __syncthreads();
        if (tid == 0) {
            resC[s] = dred[0] + dred[1] + dred[2] + dred[3];
            resS[s] = dred[4] + dred[5] + dred[6] + dred[7];
        }
    }
    __syncthreads();
    if (tid == 0) {
        const double wgt[5] = {0.0448, 0.2856, 0.3001, 0.2363, 0.1333};
        double ms = 1.0;
        for (int s = 0; s < 5; ++s) {
            int Hs = 512 >> s;
            double cnt = (double)NIMG * (double)(Hs - 10) * (double)(Hs - 10);
            double cs = resC[s] / cnt;
            double sv = resS[s] / cnt;
            if (cs < 0.0) cs = 0.0;
            if (sv < 0.0) sv = 0.0;
            cs = (cs + 1.0) * 0.5;
            sv = (sv + 1.0) * 0.5;
            ms *= pow((s < 4) ? cs : sv, wgt[s]);
        }
        out[0] = (float)(1.0 - ms);
    }
}

// ===================== single persistent fused kernel ======================
__global__ __launch_bounds__(256, 5) void ms_ssim_fused(
    const float* __restrict__ A0, const float* __restrict__ B0,
    char* __restrict__ ws, float* __restrict__ out)
{
    __shared__ __align__(16) _Float16 sm[LDSH];   // 27904 B (scalar path aliases [0,26880) as fp32)
    __shared__ float red[16];

    float2* partial = (float2*)ws;
    float*  pyr     = (float*)(ws + PYR_OFF);
    char*   bar     = ws + CNT_OFF;

    const size_t n1 = (size_t)NIMG * 256 * 256;
    const size_t n2 = (size_t)NIMG * 128 * 128;
    const size_t n3 = (size_t)NIMG * 64 * 64;
    float* pa1 = pyr;        float* pb1 = pa1 + n1;
    float* pa2 = pb1 + n1;   float* pb2 = pa2 + n2;
    float* pa3 = pb2 + n2;   float* pb3 = pa3 + n3;
    float* pa4 = pb3 + n3;   float* pb4 = pa4 + (size_t)NIMG * 32 * 32;

    // ---- wave 0: build band-weight fragment table ONCE per block --------
    if (threadIdx.x < 64) {
        const float w[11] = GWLIST;
        int base = ((threadIdx.x >> 4) << 3) - (threadIdx.x & 15);
        half8 wf;
        #pragma unroll
        for (int i = 0; i < 8; ++i) {
            int j = base + i;
            float v = 0.f;
            #pragma unroll
            for (int J = 0; J < 11; ++J) v = (j == J) ? w[J] : v;
            wf[i] = (_Float16)v;
        }
        *(half8*)&sm[WT0 + threadIdx.x * 8] = wf;
    }

    const int nb = (int)gridDim.x;

    // ---- scale 0: 512x512, 16x16x48 = 12288 tiles (MFMA path) -----------
    for (int t = blockIdx.x; t < 12288; t += nb) {
        int z = t >> 8, rem = t & 255;
        int by = rem >> 4, bx = rem & 15;
        mfma_tile(A0 + (size_t)z * (512 * 512), B0 + (size_t)z * (512 * 512),
                  512, 512, bx * 32, by * 32, z,
                  partial, t, pa1, pb1, sm, red);
    }
    grid_sync(bar, 1u, nb);

    // ---- scale 1: 256x256, 8x8x48 = 3072 tiles (MFMA path) --------------
    for (int t = blockIdx.x; t < 3072; t += nb) {
        int z = t >> 6, rem = t & 63;
        int by = rem >> 3, bx = rem & 7;
        mfma_tile(pa1 + (size_t)z * (256 * 256), pb1 + (size_t)z * (256 * 256),
                  256, 256, bx * 32, by * 32, z,
                  partial, 12288 + t, pa2, pb2, sm, red);
    }
    grid_sync(bar, 2u, nb);

    // ---- scale 2: 128x128, 4x4x48 = 768 tiles (scalar path) -------------
    for (int t = blockIdx.x; t < 768; t += nb) {
        int z = t >> 4, rem = t & 15;
        int by = rem >> 2, bx = rem & 3;
        scalar_tile(pa2 + (size_t)z * (128 * 128), pb2 + (size_t)z * (128 * 128),
                    128, 128, bx * 32, by * 32, z,
                    partial, 15360 + t, pa3, pb3, true, (float*)sm, red);
    }
    grid_sync(bar, 3u, nb);

    // ---- scale 3: 64x64, 2x2x48 = 192 tiles -----------------------------
    for (int t = blockIdx.x; t < 192; t += nb) {
        int z = t >> 2, rem = t & 3;
        int by = rem >> 1, bx = rem & 1;
        scalar_tile(pa3 + (size_t)z * (64 * 64), pb3 + (size_t)z * (64 * 64),
                    64, 64, bx * 32, by * 32, z,
                    partial, 16128 + t, pa4, pb4, true, (float*)sm, red);
    }
    grid_sync(bar, 4u, nb);

    // ---- scale 4: 32x32, 48 tiles, no pool ------------------------------
    for (int t = blockIdx.x; t < 48; t += nb) {
        scalar_tile(pa4 + (size_t)t * (32 * 32), pb4 + (size_t)t * (32 * 32),
                    32, 32, 0, 0, t,
                    partial, 16320 + t, nullptr, nullptr, false, (float*)sm, red);
    }
    grid_sync(bar, 5u, nb);

    // ---- final combine (block 0) ----------------------------------------
    if (blockIdx.x == 0) final_reduce(partial, out, sm);
}

// ---------------------------------------------------------------------------
extern "C" void kernel_launch(void* const* d_in, const int* in_sizes, int n_in,
                              void* d_out, int out_size, void* d_ws, size_t ws_size,
                              hipStream_t stream) {
    (void)in_sizes; (void)n_in; (void)out_size; (void)ws_size;
    const float* A0 = (const float*)d_in[0];
    const float* B0 = (const float*)d_in[1];
    float* out = (float*)d_out;
    char* ws = (char*)d_ws;

    // Grid sized to guaranteed co-residency (deadlock-free grid barrier):
    // occupancy query once, cached. Expect 5 blocks/CU (LDS 27.9 KB) x 256 CU.
    static int nblk = 0;
    if (nblk == 0) {
        int bpc = 0;
        if (hipOccupancyMaxActiveBlocksPerMultiprocessor(&bpc, ms_ssim_fused,
                                                         256, 0) != hipSuccess ||
            bpc < 1)
            bpc = 2;                              // ultra-conservative fallback
        int cu = 256;
        hipDeviceProp_t prop;
        int dev = 0;
        if (hipGetDevice(&dev) == hipSuccess &&
            hipGetDeviceProperties(&prop, dev) == hipSuccess &&
            prop.multiProcessorCount > 0)
            cu = prop.multiProcessorCount;
        long nb = (long)bpc * (long)cu;
        if (nb > 12288) nb = 12288;
        nblk = (int)nb;
    }

    hipMemsetAsync(ws + CNT_OFF, 0, 4096, stream);   // zero barrier state
    ms_ssim_fused<<<dim3(nblk), dim3(256), 0, stream>>>(A0, B0, ws, out);
}

// Round 5
// 212.637 us; speedup vs baseline: 2.3184x; 1.4691x over previous
//
#include <hip/hip_runtime.h>

#define HALO 10
#define NIMG 48                 // 16 batch * 3 channels

// Gaussian(sigma=1.5, 11 taps), normalized (computed offline in double).
#define GWLIST { 0.0010284f, 0.0075987f, 0.0360008f, 0.1093607f, 0.2130056f, \
                 0.2660117f, 0.2130056f, 0.1093607f, 0.0360008f, 0.0075987f, 0.0010284f }

// ======================= MFMA kernel (scales 0,1) ==========================
// fp16 pitches padded to 56 halves (112 B -> bank-stride 28, gcd(28,32)=4 ->
// 2-way aliasing = free).
// R4 change: stage 1 stores ONLY the a and b planes; a^2, b^2, ab fragments
// are built in-register at stage-2 load time (bit-identical fp16 multiply of
// the same fp16 values). Cuts 12 v_pk_mul_f16 + 3 ds_write_b128 per staging
// job and shrinks LDS; h_T gets its OWN region, removing the 2a/2b barrier
// and the res[8] register buffer.
#define PP   56                 // stage-1 plane pitch (fp16 units)
#define PSZ  (48 * 56)          // plane size = 2688 fp16
#define HT0  (2 * PSZ)          // h_T region base = 5376 fp16
#define HTP  56                 // h_T pitch along r (fp16 units)
#define HTSZ (32 * 56)          // per-quantity h_T = 1792 fp16
#define WT0  (HT0 + 5 * HTSZ)   // wfrag table offset = 14336 fp16
#define LDSH (WT0 + 64 * 8)     // 14848 fp16 = 29696 B -> 5 blocks/CU

typedef _Float16 half8 __attribute__((ext_vector_type(8)));
typedef _Float16 half4 __attribute__((ext_vector_type(4)));
typedef float    floatx4 __attribute__((ext_vector_type(4)));

// Per 32x32-output block:
//  stage 1: load 48x48 region, store a,b fp16 planes in LDS
//  stage 2: h-conv via mfma_f32_16x16x32_f16; per-job fragment built in
//           registers (q=0:a, 1:b, 2:a*a, 3:b*b, 4:a*b); result written as
//           fp16 h_T (transposed) into the dedicated h_T region
//  stage 3: v-conv via mfma, SSIM on C fragments, block reduce
//           (+ fused 2x2 avg-pool).
// Weight band fragment w[(lane>>4)*8 + i - (lane&15)] is computed by wave 0
// once into a 64-entry LDS table.
// fp16 only for scales 0-1 (cs denominators >= 0.04); deeper scales use the
// exact fp32 scalar kernel.
template <bool FUSE>
__global__ __launch_bounds__(256, 5) void ssim_mfma_kernel(
    const float* __restrict__ A, const float* __restrict__ B,
    int H, int W, float2* __restrict__ partial,
    float* __restrict__ poolA, float* __restrict__ poolB)
{
    __shared__ __align__(16) _Float16 sm[LDSH];   // 29696 B
    __shared__ float red[16];

    const float w[11] = GWLIST;
    const int tid  = threadIdx.x;
    const int lane = tid & 63;
    const int wv   = tid >> 6;
    const int gx0  = blockIdx.x * 32;
    const int gy0  = blockIdx.y * 32;
    const int z    = blockIdx.z;
    const float* a = A + (size_t)z * H * W;
    const float* b = B + (size_t)z * H * W;

    // ---- wave 0: build band-weight fragment table (64 lanes x half8) ----
    if (tid < 64) {
        int base = ((tid >> 4) << 3) - (tid & 15);
        half8 wf;
        #pragma unroll
        for (int i = 0; i < 8; ++i) {
            int j = base + i;
            float v = 0.f;
            #pragma unroll
            for (int J = 0; J < 11; ++J) v = (j == J) ? w[J] : v;
            wf[i] = (_Float16)v;
        }
        *(half8*)&sm[WT0 + tid * 8] = wf;
    }

    // ---- stage 1: 48x48 region -> 2 fp16 planes (a, b) ------------------
    const bool fast = (gy0 + 48 <= H) && (gx0 + 48 <= W);
    for (int e = tid; e < 288; e += 256) {        // 48 rows x 6 col-octets
        int r = e / 6, c8 = e - r * 6;
        float fa[8], fb[8];
        if (fast) {
            const float* pa = a + (size_t)(gy0 + r) * W + gx0 + c8 * 8;
            const float* pb = b + (size_t)(gy0 + r) * W + gx0 + c8 * 8;
            *(float4*)&fa[0] = *(const float4*)pa;
            *(float4*)&fa[4] = *(const float4*)(pa + 4);
            *(float4*)&fb[0] = *(const float4*)pb;
            *(float4*)&fb[4] = *(const float4*)(pb + 4);
        } else {
            int gy = gy0 + r;
            #pragma unroll
            for (int i = 0; i < 8; ++i) {
                int gx = gx0 + c8 * 8 + i;
                bool ok = (gy < H) && (gx < W);
                size_t idx = (size_t)gy * W + gx;
                fa[i] = ok ? a[idx] : 0.f;
                fb[i] = ok ? b[idx] : 0.f;
            }
        }
        half8 ha, hb;
        #pragma unroll
        for (int i = 0; i < 8; ++i) {
            ha[i] = (_Float16)fa[i];
            hb[i] = (_Float16)fb[i];
        }
        int o = r * PP + c8 * 8;
        *(half8*)&sm[o]       = ha;
        *(half8*)&sm[o + PSZ] = hb;
    }
    __syncthreads();

    // ---- fetch band-weight fragment (one b128 per thread) ---------------
    const half8 wfrag = *(const half8*)&sm[WT0 + lane * 8];

    // ---- stage 2: h-conv via MFMA, fragments built in registers ---------
    // job jj -> (q, m0 in {0,16,32}, x0 in {0,16}); 30 jobs over 4 waves.
    // q is wave-uniform (jj = wv + 4u with u unrolled).
    {
        const int arow = (lane & 15) * PP + ((lane >> 4) << 3);
        const int crow = (lane & 15) * HTP + ((lane >> 4) << 2);
        #pragma unroll
        for (int u = 0; u < 8; ++u) {
            int jj = wv + 4 * u;
            if (jj < 30) {                        // wave-uniform
                int q = jj / 6, rem = jj - q * 6;
                int m0 = (rem >> 1) << 4;
                int x0 = (rem & 1) << 4;
                int fb_ = m0 * PP + x0 + arow;
                half8 f;
                if (q == 0) {
                    f = *(const half8*)&sm[fb_];
                } else if (q == 1) {
                    f = *(const half8*)&sm[fb_ + PSZ];
                } else if (q == 2) {
                    half8 ha = *(const half8*)&sm[fb_];
                    f = ha * ha;                  // == stored fp16 a*a
                } else if (q == 3) {
                    half8 hb = *(const half8*)&sm[fb_ + PSZ];
                    f = hb * hb;
                } else {
                    half8 ha = *(const half8*)&sm[fb_];
                    half8 hb = *(const half8*)&sm[fb_ + PSZ];
                    f = ha * hb;
                }
                floatx4 c = {0.f, 0.f, 0.f, 0.f};
                c = __builtin_amdgcn_mfma_f32_16x16x32_f16(f, wfrag, c, 0, 0, 0);
                half4 hv;
                hv[0] = (_Float16)c[0]; hv[1] = (_Float16)c[1];
                hv[2] = (_Float16)c[2]; hv[3] = (_Float16)c[3];
                // write transposed h_T directly (own region, no hazard)
                *(half4*)&sm[HT0 + q * HTSZ + x0 * HTP + m0 + crow] = hv;
            }
        }
    }
    __syncthreads();

    // ---- stage 3: v-conv via MFMA (one 16x16 subtile per wave) + SSIM ---
    float csSum = 0.f, ssimSum = 0.f;
    {
        const int y0 = (wv >> 1) << 4;
        const int x0 = (wv & 1) << 4;
        const int brow = (lane & 15) * HTP + ((lane >> 4) << 3);
        floatx4 m[5];
        #pragma unroll
        for (int q = 0; q < 5; ++q) {
            half8 bfrag = *(const half8*)&sm[HT0 + q * HTSZ + x0 * HTP + y0 + brow];
            floatx4 c = {0.f, 0.f, 0.f, 0.f};
            m[q] = __builtin_amdgcn_mfma_f32_16x16x32_f16(wfrag, bfrag, c, 0, 0, 0);
        }
        const int OH = H - HALO, OW = W - HALO;
        const int gx  = gx0 + x0 + (lane & 15);
        const int gyb = gy0 + y0 + ((lane >> 4) << 2);
        const float C1 = 1e-4f;   // (0.01*1)^2
        const float C2 = 9e-4f;   // (0.03*1)^2
        if (gx < OW) {
            #pragma unroll
            for (int i = 0; i < 4; ++i) {
                int gy = gyb + i;
                if (gy < OH) {
                    float mu1 = m[0][i], mu2 = m[1][i];
                    float s1sq = m[2][i] - mu1 * mu1;
                    float s2sq = m[3][i] - mu2 * mu2;
                    float s12  = m[4][i] - mu1 * mu2;
                    float denom = s1sq + s2sq + C2;
                    float num   = 2.f * s12 + C2;
                    float csv = num * __frcp_rn(denom);
                    float ssv = csv * (2.f * mu1 * mu2 + C1) *
                                __frcp_rn(mu1 * mu1 + mu2 * mu2 + C1);
                    csSum   += csv;
                    ssimSum += ssv;
                }
            }
        }
    }

    // ---- block reduction -> per-block partial slot ----------------------
    #pragma unroll
    for (int off = 32; off > 0; off >>= 1) {
        csSum   += __shfl_down(csSum, off, 64);
        ssimSum += __shfl_down(ssimSum, off, 64);
    }
    if (lane == 0) {
        red[wv]     = csSum;
        red[8 + wv] = ssimSum;
    }
    __syncthreads();
    if (tid == 0) {
        float c = 0.f, s = 0.f;
        #pragma unroll
        for (int i = 0; i < 4; ++i) { c += red[i]; s += red[8 + i]; }
        int slot = (z * gridDim.y + blockIdx.y) * gridDim.x + blockIdx.x;
        partial[slot] = make_float2(c, s);
    }

    // ---- fused 2x2 avg-pool of this block's own 32x32 input region ------
    if (FUSE && tid < 128) {
        const int OH2 = H >> 1, OW2 = W >> 1;
        const int img = tid >> 6;            // 0 = A, 1 = B
        const int rem = tid & 63;
        const int pr  = rem >> 2;            // pooled row 0..15
        const int pq  = rem & 3;             // pooled float4-col 0..3
        const float* src = img ? b : a;
        float* dst = (img ? poolB : poolA) + (size_t)z * OH2 * OW2;
        size_t base = (size_t)(gy0 + 2 * pr) * W + gx0 + pq * 8;
        float4 r0 = *(const float4*)(src + base);
        float4 r1 = *(const float4*)(src + base + 4);
        float4 r2 = *(const float4*)(src + base + W);
        float4 r3 = *(const float4*)(src + base + W + 4);
        float4 o;
        o.x = 0.25f * (r0.x + r0.y + r2.x + r2.y);
        o.y = 0.25f * (r0.z + r0.w + r2.z + r2.w);
        o.z = 0.25f * (r1.x + r1.y + r3.x + r3.y);
        o.w = 0.25f * (r1.z + r1.w + r3.z + r3.w);
        *(float4*)(dst + (size_t)((gy0 >> 1) + pr) * OW2 + (gx0 >> 1) + pq * 4) = o;
    }
}

// ================= exact fp32 scalar kernel (scales 2-4) ===================
#define TH   32
#define ROWS (TH + HALO)      // 42
#define HSTR 32
#define HQ   (ROWS * HSTR)    // 1344 floats

template <bool FUSE>
__global__ __launch_bounds__(256, 5) void ssim_scalar_kernel(
    const float* __restrict__ A, const float* __restrict__ B,
    int H, int W, float2* __restrict__ partial,
    float* __restrict__ poolA, float* __restrict__ poolB)
{
    __shared__ __align__(16) float lds[5 * HQ];   // 26880 B
    __shared__ float red[16];

    const float w[11] = GWLIST;

    const int tid = threadIdx.x;
    const int gx0 = blockIdx.x * 32;
    const int gy0 = blockIdx.y * TH;
    const int z   = blockIdx.z;
    const float* a = A + (size_t)z * H * W;
    const float* b = B + (size_t)z * H * W;

    const bool fast = (gy0 + ROWS <= H) && (gx0 + 44 <= W);
    for (int e = tid; e < ROWS * 8; e += 256) {
        int r = e >> 3, c0 = (e & 7) * 4;
        int gy = gy0 + r;
        float s1[4]  = {0.f, 0.f, 0.f, 0.f};
        float s2[4]  = {0.f, 0.f, 0.f, 0.f};
        float s11[4] = {0.f, 0.f, 0.f, 0.f};
        float s22[4] = {0.f, 0.f, 0.f, 0.f};
        float s12[4] = {0.f, 0.f, 0.f, 0.f};
        #pragma unroll
        for (int c = 0; c < 4; ++c) {
            float ea[4], eb[4];
            if (fast) {
                const float* pa = a + (size_t)gy * W + gx0 + c0 + 4 * c;
                const float* pb = b + (size_t)gy * W + gx0 + c0 + 4 * c;
                *(float4*)&ea[0] = *(const float4*)pa;
                *(float4*)&eb[0] = *(const float4*)pb;
            } else {
                #pragma unroll
                for (int t = 0; t < 4; ++t) {
                    int gx = gx0 + c0 + 4 * c + t;
                    bool ok = (gy < H) && (gx < W);
                    size_t idx = (size_t)gy * W + gx;
                    ea[t] = ok ? a[idx] : 0.f;
                    eb[t] = ok ? b[idx] : 0.f;
                }
            }
            #pragma unroll
            for (int mm = 0; mm < 4; ++mm) {
                const int i = 4 * c + mm;
                float va = ea[mm], vb = eb[mm];
                float vaa = va * va, vbb = vb * vb, vab = va * vb;
                #pragma unroll
                for (int k = 0; k < 4; ++k) {
                    const int j = i - k;
                    if (j >= 0 && j <= 10) {
                        float wj = w[j];
                        s1[k]  += wj * va;
                        s2[k]  += wj * vb;
                        s11[k] += wj * vaa;
                        s22[k] += wj * vbb;
                        s12[k] += wj * vab;
                    }
                }
            }
        }
        int hb = r * HSTR + c0;
        *(float4*)&lds[hb + 0 * HQ] = make_float4(s1[0],  s1[1],  s1[2],  s1[3]);
        *(float4*)&lds[hb + 1 * HQ] = make_float4(s2[0],  s2[1],  s2[2],  s2[3]);
        *(float4*)&lds[hb + 2 * HQ] = make_float4(s11[0], s11[1], s11[2], s11[3]);
        *(float4*)&lds[hb + 3 * HQ] = make_float4(s22[0], s22[1], s22[2], s22[3]);
        *(float4*)&lds[hb + 4 * HQ] = make_float4(s12[0], s12[1], s12[2], s12[3]);
    }
    __syncthreads();

    const float C1 = 1e-4f;
    const float C2 = 9e-4f;
    float csSum = 0.f, ssimSum = 0.f;
    {
        const int ox  = tid & 31;
        const int oy0 = (tid >> 5) * 4;
        float m[5][4];
        #pragma unroll
        for (int q = 0; q < 5; ++q) {
            const float* hq = &lds[q * HQ + oy0 * HSTR + ox];
            float win[14];
            #pragma unroll
            for (int i = 0; i < 14; ++i) win[i] = hq[i * HSTR];
            #pragma unroll
            for (int k = 0; k < 4; ++k) {
                float acc = 0.f;
                #pragma unroll
                for (int j = 0; j < 11; ++j) acc += w[j] * win[k + j];
                m[q][k] = acc;
            }
        }
        const int OH = H - HALO, OW = W - HALO;
        const int gx = gx0 + ox;
        #pragma unroll
        for (int k = 0; k < 4; ++k) {
            int gy = gy0 + oy0 + k;
            if (gy < OH && gx < OW) {
                float mu1 = m[0][k], mu2 = m[1][k];
                float s1sq = m[2][k] - mu1 * mu1;
                float s2sq = m[3][k] - mu2 * mu2;
                float s12  = m[4][k] - mu1 * mu2;
                float denom  = s1sq + s2sq + C2;
                float num_cs = 2.f * s12 + C2;
                float csv = num_cs * __frcp_rn(denom);
                float ssv = csv * (2.f * mu1 * mu2 + C1) *
                            __frcp_rn(mu1 * mu1 + mu2 * mu2 + C1);
                csSum   += csv;
                ssimSum += ssv;
            }
        }
    }

    #pragma unroll
    for (int off = 32; off > 0; off >>= 1) {
        csSum   += __shfl_down(csSum, off, 64);
        ssimSum += __shfl_down(ssimSum, off, 64);
    }
    int wave = tid >> 6, lane = tid & 63;
    if (lane == 0) {
        red[wave]     = csSum;
        red[8 + wave] = ssimSum;
    }
    __syncthreads();
    if (tid == 0) {
        float c = 0.f, s = 0.f;
        #pragma unroll
        for (int i = 0; i < 4; ++i) { c += red[i]; s += red[8 + i]; }
        int slot = (z * gridDim.y + blockIdx.y) * gridDim.x + blockIdx.x;
        partial[slot] = make_float2(c, s);
    }

    if (FUSE && tid < 128) {
        const int OH2 = H >> 1, OW2 = W >> 1;
        const int img = tid >> 6;
        const int rem = tid & 63;
        const int pr  = rem >> 2;
        const int pq  = rem & 3;
        const float* src = img ? b : a;
        float* dst = (img ? poolB : poolA) + (size_t)z * OH2 * OW2;
        size_t base = (size_t)(gy0 + 2 * pr) * W + gx0 + pq * 8;
        float4 r0 = *(const float4*)(src + base);
        float4 r1 = *(const float4*)(src + base + 4);
        float4 r2 = *(const float4*)(src + base + W);
        float4 r3 = *(const float4*)(src + base + W + 4);
        float4 o;
        o.x = 0.25f * (r0.x + r0.y + r2.x + r2.y);
        o.y = 0.25f * (r0.z + r0.w + r2.z + r2.w);
        o.z = 0.25f * (r1.x + r1.y + r3.x + r3.y);
        o.w = 0.25f * (r1.z + r1.w + r3.z + r3.w);
        *(float4*)(dst + (size_t)((gy0 >> 1) + pr) * OW2 + (gx0 >> 1) + pq * 4) = o;
    }
}

// ---------------------------------------------------------------------------
// Reduce all per-block partials (5 segments) and combine.
__global__ void final_kernel(const float2* __restrict__ partial, float* __restrict__ out) {
    __shared__ double red[8];
    __shared__ double resC[5], resS[5];
    const int segs[6] = {0, 12288, 15360, 16128, 16320, 16368};
    const int tid = threadIdx.x;
    for (int s = 0; s < 5; ++s) {
        double c = 0.0, v = 0.0;
        #pragma unroll 4
        for (int i = segs[s] + tid; i < segs[s + 1]; i += 256) {
            float2 p = partial[i];
            c += (double)p.x;
            v += (double)p.y;
        }
        #pragma unroll
        for (int off = 32; off > 0; off >>= 1) {
            c += __shfl_down(c, off, 64);
            v += __shfl_down(v, off, 64);
        }
        int wave = tid >> 6, lane = tid & 63;
        __syncthreads();
        if (lane == 0) { red[wave] = c; red[4 + wave] = v; }
        __syncthreads();
        if (tid == 0) {
            resC[s] = red[0] + red[1] + red[2] + red[3];
            resS[s] = red[4] + red[5] + red[6] + red[7];
        }
    }
    __syncthreads();
    if (tid == 0) {
        const double wgt[5] = {0.0448, 0.2856, 0.3001, 0.2363, 0.1333};
        double ms = 1.0;
        for (int s = 0; s < 5; ++s) {
            int Hs = 512 >> s;
            double cnt = (double)NIMG * (double)(Hs - 10) * (double)(Hs - 10);
            double cs = resC[s] / cnt;
            double sv = resS[s] / cnt;
            if (cs < 0.0) cs = 0.0;
            if (sv < 0.0) sv = 0.0;
            cs = (cs + 1.0) * 0.5;
            sv = (sv + 1.0) * 0.5;
            ms *= pow((s < 4) ? cs : sv, wgt[s]);
        }
        out[0] = (float)(1.0 - ms);
    }
}

// ---------------------------------------------------------------------------
extern "C" void kernel_launch(void* const* d_in, const int* in_sizes, int n_in,
                              void* d_out, int out_size, void* d_ws, size_t ws_size,
                              hipStream_t stream) {
    (void)in_sizes; (void)n_in; (void)out_size; (void)ws_size;
    const float* A0 = (const float*)d_in[0];
    const float* B0 = (const float*)d_in[1];
    float* out = (float*)d_out;

    char* ws = (char*)d_ws;
    float2* partial = (float2*)ws;             // 16368 float2 = 131 KB
    float* pyr = (float*)(ws + (1 << 18));     // 256 KB offset

    float* pa[5] = {nullptr, nullptr, nullptr, nullptr, nullptr};
    float* pb[5] = {nullptr, nullptr, nullptr, nullptr, nullptr};
    size_t off = 0;
    for (int s = 1; s <= 4; ++s) {
        int Hs = 512 >> s;
        size_t n = (size_t)NIMG * Hs * Hs;
        pa[s] = pyr + off; off += n;
        pb[s] = pyr + off; off += n;
    }

    const int segs[5] = {0, 12288, 15360, 16128, 16320};

    const float* curA = A0;
    const float* curB = B0;
    for (int s = 0; s < 5; ++s) {
        int Hs = 512 >> s;
        int g  = Hs >> 5;                      // tiles exactly cover image
        dim3 grid(g, g, NIMG);
        if (s < 2) {
            ssim_mfma_kernel<true><<<grid, 256, 0, stream>>>(
                curA, curB, Hs, Hs, partial + segs[s], pa[s + 1], pb[s + 1]);
            curA = pa[s + 1];
            curB = pb[s + 1];
        } else if (s < 4) {
            ssim_scalar_kernel<true><<<grid, 256, 0, stream>>>(
                curA, curB, Hs, Hs, partial + segs[s], pa[s + 1], pb[s + 1]);
            curA = pa[s + 1];
            curB = pb[s + 1];
        } else {
            ssim_scalar_kernel<false><<<grid, 256, 0, stream>>>(
                curA, curB, Hs, Hs, partial + segs[s], nullptr, nullptr);
        }
    }

    final_kernel<<<1, 256, 0, stream>>>(partial, out);
}

// Round 6
// 208.688 us; speedup vs baseline: 2.3623x; 1.0189x over previous
//
#include <hip/hip_runtime.h>

#define HALO 10
#define NIMG 48                 // 16 batch * 3 channels

// Gaussian(sigma=1.5, 11 taps), normalized (computed offline in double).
#define GWLIST { 0.0010284f, 0.0075987f, 0.0360008f, 0.1093607f, 0.2130056f, \
                 0.2660117f, 0.2130056f, 0.1093607f, 0.0360008f, 0.0075987f, 0.0010284f }

// ======================= MFMA kernel (scales 0,1) ==========================
// fp16 pitches padded to 56 halves (112 B -> bank-stride 28, gcd(28,32)=4 ->
// 2-way aliasing = free).
// R4: stage 1 stores ONLY a,b planes; a^2/b^2/ab built in-register (bit-
// identical fp16 products). R4 POST-MORTEM: runtime 5-way q-branch in the
// unrolled job loop broke pipelining (72->79.5us despite less VALU work).
// R5 fix: iterate by POSITION, branch-free: per position 2 ds_reads ->
// 3 pk_mul -> 5 INDEPENDENT MFMAs -> 5 h_T writes. Same math, max ILP.
#define PP   56                 // stage-1 plane pitch (fp16 units)
#define PSZ  (48 * 56)          // plane size = 2688 fp16
#define HT0  (2 * PSZ)          // h_T region base = 5376 fp16
#define HTP  56                 // h_T pitch along r (fp16 units)
#define HTSZ (32 * 56)          // per-quantity h_T = 1792 fp16
#define WT0  (HT0 + 5 * HTSZ)   // wfrag table offset = 14336 fp16
#define LDSH (WT0 + 64 * 8)     // 14848 fp16 = 29696 B -> 5 blocks/CU

typedef _Float16 half8 __attribute__((ext_vector_type(8)));
typedef _Float16 half4 __attribute__((ext_vector_type(4)));
typedef float    floatx4 __attribute__((ext_vector_type(4)));

template <bool FUSE>
__global__ __launch_bounds__(256, 5) void ssim_mfma_kernel(
    const float* __restrict__ A, const float* __restrict__ B,
    int H, int W, float2* __restrict__ partial,
    float* __restrict__ poolA, float* __restrict__ poolB)
{
    __shared__ __align__(16) _Float16 sm[LDSH];   // 29696 B
    __shared__ float red[16];

    const float w[11] = GWLIST;
    const int tid  = threadIdx.x;
    const int lane = tid & 63;
    const int wv   = tid >> 6;
    const int gx0  = blockIdx.x * 32;
    const int gy0  = blockIdx.y * 32;
    const int z    = blockIdx.z;
    const float* a = A + (size_t)z * H * W;
    const float* b = B + (size_t)z * H * W;

    // ---- wave 0: build band-weight fragment table (64 lanes x half8) ----
    if (tid < 64) {
        int base = ((tid >> 4) << 3) - (tid & 15);
        half8 wf;
        #pragma unroll
        for (int i = 0; i < 8; ++i) {
            int j = base + i;
            float v = 0.f;
            #pragma unroll
            for (int J = 0; J < 11; ++J) v = (j == J) ? w[J] : v;
            wf[i] = (_Float16)v;
        }
        *(half8*)&sm[WT0 + tid * 8] = wf;
    }

    // ---- stage 1: 48x48 region -> 2 fp16 planes (a, b) ------------------
    const bool fast = (gy0 + 48 <= H) && (gx0 + 48 <= W);
    for (int e = tid; e < 288; e += 256) {        // 48 rows x 6 col-octets
        int r = e / 6, c8 = e - r * 6;
        float fa[8], fb[8];
        if (fast) {
            const float* pa = a + (size_t)(gy0 + r) * W + gx0 + c8 * 8;
            const float* pb = b + (size_t)(gy0 + r) * W + gx0 + c8 * 8;
            *(float4*)&fa[0] = *(const float4*)pa;
            *(float4*)&fa[4] = *(const float4*)(pa + 4);
            *(float4*)&fb[0] = *(const float4*)pb;
            *(float4*)&fb[4] = *(const float4*)(pb + 4);
        } else {
            int gy = gy0 + r;
            #pragma unroll
            for (int i = 0; i < 8; ++i) {
                int gx = gx0 + c8 * 8 + i;
                bool ok = (gy < H) && (gx < W);
                size_t idx = (size_t)gy * W + gx;
                fa[i] = ok ? a[idx] : 0.f;
                fb[i] = ok ? b[idx] : 0.f;
            }
        }
        half8 ha, hb;
        #pragma unroll
        for (int i = 0; i < 8; ++i) {
            ha[i] = (_Float16)fa[i];
            hb[i] = (_Float16)fb[i];
        }
        int o = r * PP + c8 * 8;
        *(half8*)&sm[o]       = ha;
        *(half8*)&sm[o + PSZ] = hb;
    }
    __syncthreads();

    // ---- fetch band-weight fragment (one b128 per thread) ---------------
    const half8 wfrag = *(const half8*)&sm[WT0 + lane * 8];

    // ---- stage 2: h-conv via MFMA, branch-free per-position -------------
    // position p -> (m0 in {0,16,32}, x0 in {0,16}); 6 positions, waves
    // 0-1 take 2, waves 2-3 take 1. Per position: 2 ds_read_b128 ->
    // 3 v_pk_mul_f16 x4 -> 5 independent MFMAs -> 5 half4 h_T writes.
    {
        const int arow = (lane & 15) * PP + ((lane >> 4) << 3);
        const int crow = (lane & 15) * HTP + ((lane >> 4) << 2);
        #pragma unroll 2
        for (int p = wv; p < 6; p += 4) {
            int m0 = (p >> 1) << 4;
            int x0 = (p & 1) << 4;
            int fb_ = m0 * PP + x0 + arow;
            half8 ha  = *(const half8*)&sm[fb_];
            half8 hb  = *(const half8*)&sm[fb_ + PSZ];
            half8 faa = ha * ha;                  // == stored fp16 a*a
            half8 fbb = hb * hb;
            half8 fab = ha * hb;
            floatx4 zero = {0.f, 0.f, 0.f, 0.f};
            floatx4 c0 = __builtin_amdgcn_mfma_f32_16x16x32_f16(ha,  wfrag, zero, 0, 0, 0);
            floatx4 c1 = __builtin_amdgcn_mfma_f32_16x16x32_f16(hb,  wfrag, zero, 0, 0, 0);
            floatx4 c2 = __builtin_amdgcn_mfma_f32_16x16x32_f16(faa, wfrag, zero, 0, 0, 0);
            floatx4 c3 = __builtin_amdgcn_mfma_f32_16x16x32_f16(fbb, wfrag, zero, 0, 0, 0);
            floatx4 c4 = __builtin_amdgcn_mfma_f32_16x16x32_f16(fab, wfrag, zero, 0, 0, 0);
            int cb = HT0 + x0 * HTP + m0 + crow;
            half4 h0, h1, h2, h3, h4;
            #pragma unroll
            for (int i = 0; i < 4; ++i) {
                h0[i] = (_Float16)c0[i];
                h1[i] = (_Float16)c1[i];
                h2[i] = (_Float16)c2[i];
                h3[i] = (_Float16)c3[i];
                h4[i] = (_Float16)c4[i];
            }
            *(half4*)&sm[cb + 0 * HTSZ] = h0;
            *(half4*)&sm[cb + 1 * HTSZ] = h1;
            *(half4*)&sm[cb + 2 * HTSZ] = h2;
            *(half4*)&sm[cb + 3 * HTSZ] = h3;
            *(half4*)&sm[cb + 4 * HTSZ] = h4;
        }
    }
    __syncthreads();

    // ---- stage 3: v-conv via MFMA (one 16x16 subtile per wave) + SSIM ---
    float csSum = 0.f, ssimSum = 0.f;
    {
        const int y0 = (wv >> 1) << 4;
        const int x0 = (wv & 1) << 4;
        const int brow = (lane & 15) * HTP + ((lane >> 4) << 3);
        floatx4 m[5];
        #pragma unroll
        for (int q = 0; q < 5; ++q) {
            half8 bfrag = *(const half8*)&sm[HT0 + q * HTSZ + x0 * HTP + y0 + brow];
            floatx4 c = {0.f, 0.f, 0.f, 0.f};
            m[q] = __builtin_amdgcn_mfma_f32_16x16x32_f16(wfrag, bfrag, c, 0, 0, 0);
        }
        const int OH = H - HALO, OW = W - HALO;
        const int gx  = gx0 + x0 + (lane & 15);
        const int gyb = gy0 + y0 + ((lane >> 4) << 2);
        const float C1 = 1e-4f;   // (0.01*1)^2
        const float C2 = 9e-4f;   // (0.03*1)^2
        if (gx < OW) {
            #pragma unroll
            for (int i = 0; i < 4; ++i) {
                int gy = gyb + i;
                if (gy < OH) {
                    float mu1 = m[0][i], mu2 = m[1][i];
                    float s1sq = m[2][i] - mu1 * mu1;
                    float s2sq = m[3][i] - mu2 * mu2;
                    float s12  = m[4][i] - mu1 * mu2;
                    float denom = s1sq + s2sq + C2;
                    float num   = 2.f * s12 + C2;
                    float csv = num * __frcp_rn(denom);
                    float ssv = csv * (2.f * mu1 * mu2 + C1) *
                                __frcp_rn(mu1 * mu1 + mu2 * mu2 + C1);
                    csSum   += csv;
                    ssimSum += ssv;
                }
            }
        }
    }

    // ---- block reduction -> per-block partial slot ----------------------
    #pragma unroll
    for (int off = 32; off > 0; off >>= 1) {
        csSum   += __shfl_down(csSum, off, 64);
        ssimSum += __shfl_down(ssimSum, off, 64);
    }
    if (lane == 0) {
        red[wv]     = csSum;
        red[8 + wv] = ssimSum;
    }
    __syncthreads();
    if (tid == 0) {
        float c = 0.f, s = 0.f;
        #pragma unroll
        for (int i = 0; i < 4; ++i) { c += red[i]; s += red[8 + i]; }
        int slot = (z * gridDim.y + blockIdx.y) * gridDim.x + blockIdx.x;
        partial[slot] = make_float2(c, s);
    }

    // ---- fused 2x2 avg-pool of this block's own 32x32 input region ------
    if (FUSE && tid < 128) {
        const int OH2 = H >> 1, OW2 = W >> 1;
        const int img = tid >> 6;            // 0 = A, 1 = B
        const int rem = tid & 63;
        const int pr  = rem >> 2;            // pooled row 0..15
        const int pq  = rem & 3;             // pooled float4-col 0..3
        const float* src = img ? b : a;
        float* dst = (img ? poolB : poolA) + (size_t)z * OH2 * OW2;
        size_t base = (size_t)(gy0 + 2 * pr) * W + gx0 + pq * 8;
        float4 r0 = *(const float4*)(src + base);
        float4 r1 = *(const float4*)(src + base + 4);
        float4 r2 = *(const float4*)(src + base + W);
        float4 r3 = *(const float4*)(src + base + W + 4);
        float4 o;
        o.x = 0.25f * (r0.x + r0.y + r2.x + r2.y);
        o.y = 0.25f * (r0.z + r0.w + r2.z + r2.w);
        o.z = 0.25f * (r1.x + r1.y + r3.x + r3.y);
        o.w = 0.25f * (r1.z + r1.w + r3.z + r3.w);
        *(float4*)(dst + (size_t)((gy0 >> 1) + pr) * OW2 + (gx0 >> 1) + pq * 4) = o;
    }
}

// ================= exact fp32 scalar kernel (scales 2-4) ===================
#define TH   32
#define ROWS (TH + HALO)      // 42
#define HSTR 32
#define HQ   (ROWS * HSTR)    // 1344 floats

template <bool FUSE>
__global__ __launch_bounds__(256, 5) void ssim_scalar_kernel(
    const float* __restrict__ A, const float* __restrict__ B,
    int H, int W, float2* __restrict__ partial,
    float* __restrict__ poolA, float* __restrict__ poolB)
{
    __shared__ __align__(16) float lds[5 * HQ];   // 26880 B
    __shared__ float red[16];

    const float w[11] = GWLIST;

    const int tid = threadIdx.x;
    const int gx0 = blockIdx.x * 32;
    const int gy0 = blockIdx.y * TH;
    const int z   = blockIdx.z;
    const float* a = A + (size_t)z * H * W;
    const float* b = B + (size_t)z * H * W;

    const bool fast = (gy0 + ROWS <= H) && (gx0 + 44 <= W);
    for (int e = tid; e < ROWS * 8; e += 256) {
        int r = e >> 3, c0 = (e & 7) * 4;
        int gy = gy0 + r;
        float s1[4]  = {0.f, 0.f, 0.f, 0.f};
        float s2[4]  = {0.f, 0.f, 0.f, 0.f};
        float s11[4] = {0.f, 0.f, 0.f, 0.f};
        float s22[4] = {0.f, 0.f, 0.f, 0.f};
        float s12[4] = {0.f, 0.f, 0.f, 0.f};
        #pragma unroll
        for (int c = 0; c < 4; ++c) {
            float ea[4], eb[4];
            if (fast) {
                const float* pa = a + (size_t)gy * W + gx0 + c0 + 4 * c;
                const float* pb = b + (size_t)gy * W + gx0 + c0 + 4 * c;
                *(float4*)&ea[0] = *(const float4*)pa;
                *(float4*)&eb[0] = *(const float4*)pb;
            } else {
                #pragma unroll
                for (int t = 0; t < 4; ++t) {
                    int gx = gx0 + c0 + 4 * c + t;
                    bool ok = (gy < H) && (gx < W);
                    size_t idx = (size_t)gy * W + gx;
                    ea[t] = ok ? a[idx] : 0.f;
                    eb[t] = ok ? b[idx] : 0.f;
                }
            }
            #pragma unroll
            for (int mm = 0; mm < 4; ++mm) {
                const int i = 4 * c + mm;
                float va = ea[mm], vb = eb[mm];
                float vaa = va * va, vbb = vb * vb, vab = va * vb;
                #pragma unroll
                for (int k = 0; k < 4; ++k) {
                    const int j = i - k;
                    if (j >= 0 && j <= 10) {
                        float wj = w[j];
                        s1[k]  += wj * va;
                        s2[k]  += wj * vb;
                        s11[k] += wj * vaa;
                        s22[k] += wj * vbb;
                        s12[k] += wj * vab;
                    }
                }
            }
        }
        int hb = r * HSTR + c0;
        *(float4*)&lds[hb + 0 * HQ] = make_float4(s1[0],  s1[1],  s1[2],  s1[3]);
        *(float4*)&lds[hb + 1 * HQ] = make_float4(s2[0],  s2[1],  s2[2],  s2[3]);
        *(float4*)&lds[hb + 2 * HQ] = make_float4(s11[0], s11[1], s11[2], s11[3]);
        *(float4*)&lds[hb + 3 * HQ] = make_float4(s22[0], s22[1], s22[2], s22[3]);
        *(float4*)&lds[hb + 4 * HQ] = make_float4(s12[0], s12[1], s12[2], s12[3]);
    }
    __syncthreads();

    const float C1 = 1e-4f;
    const float C2 = 9e-4f;
    float csSum = 0.f, ssimSum = 0.f;
    {
        const int ox  = tid & 31;
        const int oy0 = (tid >> 5) * 4;
        float m[5][4];
        #pragma unroll
        for (int q = 0; q < 5; ++q) {
            const float* hq = &lds[q * HQ + oy0 * HSTR + ox];
            float win[14];
            #pragma unroll
            for (int i = 0; i < 14; ++i) win[i] = hq[i * HSTR];
            #pragma unroll
            for (int k = 0; k < 4; ++k) {
                float acc = 0.f;
                #pragma unroll
                for (int j = 0; j < 11; ++j) acc += w[j] * win[k + j];
                m[q][k] = acc;
            }
        }
        const int OH = H - HALO, OW = W - HALO;
        const int gx = gx0 + ox;
        #pragma unroll
        for (int k = 0; k < 4; ++k) {
            int gy = gy0 + oy0 + k;
            if (gy < OH && gx < OW) {
                float mu1 = m[0][k], mu2 = m[1][k];
                float s1sq = m[2][k] - mu1 * mu1;
                float s2sq = m[3][k] - mu2 * mu2;
                float s12  = m[4][k] - mu1 * mu2;
                float denom  = s1sq + s2sq + C2;
                float num_cs = 2.f * s12 + C2;
                float csv = num_cs * __frcp_rn(denom);
                float ssv = csv * (2.f * mu1 * mu2 + C1) *
                            __frcp_rn(mu1 * mu1 + mu2 * mu2 + C1);
                csSum   += csv;
                ssimSum += ssv;
            }
        }
    }

    #pragma unroll
    for (int off = 32; off > 0; off >>= 1) {
        csSum   += __shfl_down(csSum, off, 64);
        ssimSum += __shfl_down(ssimSum, off, 64);
    }
    int wave = tid >> 6, lane = tid & 63;
    if (lane == 0) {
        red[wave]     = csSum;
        red[8 + wave] = ssimSum;
    }
    __syncthreads();
    if (tid == 0) {
        float c = 0.f, s = 0.f;
        #pragma unroll
        for (int i = 0; i < 4; ++i) { c += red[i]; s += red[8 + i]; }
        int slot = (z * gridDim.y + blockIdx.y) * gridDim.x + blockIdx.x;
        partial[slot] = make_float2(c, s);
    }

    if (FUSE && tid < 128) {
        const int OH2 = H >> 1, OW2 = W >> 1;
        const int img = tid >> 6;
        const int rem = tid & 63;
        const int pr  = rem >> 2;
        const int pq  = rem & 3;
        const float* src = img ? b : a;
        float* dst = (img ? poolB : poolA) + (size_t)z * OH2 * OW2;
        size_t base = (size_t)(gy0 + 2 * pr) * W + gx0 + pq * 8;
        float4 r0 = *(const float4*)(src + base);
        float4 r1 = *(const float4*)(src + base + 4);
        float4 r2 = *(const float4*)(src + base + W);
        float4 r3 = *(const float4*)(src + base + W + 4);
        float4 o;
        o.x = 0.25f * (r0.x + r0.y + r2.x + r2.y);
        o.y = 0.25f * (r0.z + r0.w + r2.z + r2.w);
        o.z = 0.25f * (r1.x + r1.y + r3.x + r3.y);
        o.w = 0.25f * (r1.z + r1.w + r3.z + r3.w);
        *(float4*)(dst + (size_t)((gy0 >> 1) + pr) * OW2 + (gx0 >> 1) + pq * 4) = o;
    }
}

// ---------------------------------------------------------------------------
// Reduce all per-block partials (5 segments) and combine.
__global__ void final_kernel(const float2* __restrict__ partial, float* __restrict__ out) {
    __shared__ double red[8];
    __shared__ double resC[5], resS[5];
    const int segs[6] = {0, 12288, 15360, 16128, 16320, 16368};
    const int tid = threadIdx.x;
    for (int s = 0; s < 5; ++s) {
        double c = 0.0, v = 0.0;
        #pragma unroll 4
        for (int i = segs[s] + tid; i < segs[s + 1]; i += 256) {
            float2 p = partial[i];
            c += (double)p.x;
            v += (double)p.y;
        }
        #pragma unroll
        for (int off = 32; off > 0; off >>= 1) {
            c += __shfl_down(c, off, 64);
            v += __shfl_down(v, off, 64);
        }
        int wave = tid >> 6, lane = tid & 63;
        __syncthreads();
        if (lane == 0) { red[wave] = c; red[4 + wave] = v; }
        __syncthreads();
        if (tid == 0) {
            resC[s] = red[0] + red[1] + red[2] + red[3];
            resS[s] = red[4] + red[5] + red[6] + red[7];
        }
    }
    __syncthreads();
    if (tid == 0) {
        const double wgt[5] = {0.0448, 0.2856, 0.3001, 0.2363, 0.1333};
        double ms = 1.0;
        for (int s = 0; s < 5; ++s) {
            int Hs = 512 >> s;
            double cnt = (double)NIMG * (double)(Hs - 10) * (double)(Hs - 10);
            double cs = resC[s] / cnt;
            double sv = resS[s] / cnt;
            if (cs < 0.0) cs = 0.0;
            if (sv < 0.0) sv = 0.0;
            cs = (cs + 1.0) * 0.5;
            sv = (sv + 1.0) * 0.5;
            ms *= pow((s < 4) ? cs : sv, wgt[s]);
        }
        out[0] = (float)(1.0 - ms);
    }
}

// ---------------------------------------------------------------------------
extern "C" void kernel_launch(void* const* d_in, const int* in_sizes, int n_in,
                              void* d_out, int out_size, void* d_ws, size_t ws_size,
                              hipStream_t stream) {
    (void)in_sizes; (void)n_in; (void)out_size; (void)ws_size;
    const float* A0 = (const float*)d_in[0];
    const float* B0 = (const float*)d_in[1];
    float* out = (float*)d_out;

    char* ws = (char*)d_ws;
    float2* partial = (float2*)ws;             // 16368 float2 = 131 KB
    float* pyr = (float*)(ws + (1 << 18));     // 256 KB offset

    float* pa[5] = {nullptr, nullptr, nullptr, nullptr, nullptr};
    float* pb[5] = {nullptr, nullptr, nullptr, nullptr, nullptr};
    size_t off = 0;
    for (int s = 1; s <= 4; ++s) {
        int Hs = 512 >> s;
        size_t n = (size_t)NIMG * Hs * Hs;
        pa[s] = pyr + off; off += n;
        pb[s] = pyr + off; off += n;
    }

    const int segs[5] = {0, 12288, 15360, 16128, 16320};

    const float* curA = A0;
    const float* curB = B0;
    for (int s = 0; s < 5; ++s) {
        int Hs = 512 >> s;
        int g  = Hs >> 5;                      // tiles exactly cover image
        dim3 grid(g, g, NIMG);
        if (s < 2) {
            ssim_mfma_kernel<true><<<grid, 256, 0, stream>>>(
                curA, curB, Hs, Hs, partial + segs[s], pa[s + 1], pb[s + 1]);
            curA = pa[s + 1];
            curB = pb[s + 1];
        } else if (s < 4) {
            ssim_scalar_kernel<true><<<grid, 256, 0, stream>>>(
                curA, curB, Hs, Hs, partial + segs[s], pa[s + 1], pb[s + 1]);
            curA = pa[s + 1];
            curB = pb[s + 1];
        } else {
            ssim_scalar_kernel<false><<<grid, 256, 0, stream>>>(
                curA, curB, Hs, Hs, partial + segs[s], nullptr, nullptr);
        }
    }

    final_kernel<<<1, 256, 0, stream>>>(partial, out);
}